// Round 12
// baseline (242.855 us; speedup 1.0000x reference)
//
#include <hip/hip_runtime.h>
#include <hip/hip_bf16.h>
#include <math.h>

#define BB 32
#define SS 2048
#define HE 1024
#define HD 1024
#define WROW (HE + HD)   // 2048

typedef __attribute__((ext_vector_type(8))) short bf16x8;
typedef __attribute__((ext_vector_type(4))) float f32x4;
typedef __attribute__((ext_vector_type(16))) float f32x16;
typedef __attribute__((ext_vector_type(8))) unsigned short u16x8;

__device__ __forceinline__ unsigned short f2bf(float f) {
    union { float f; unsigned u; } v; v.f = f;
    unsigned r = v.u + 0x7fffu + ((v.u >> 16) & 1u);   // RNE
    return (unsigned short)(r >> 16);
}

__device__ __forceinline__ unsigned int pk2(float x, float y) {
    union { __hip_bfloat162 h; unsigned int u; } c;
    c.h = __float22bfloat162_rn(float2{x, y});          // v_cvt_pk_bf16_f32
    return c.u;
}

#define LGKM0()  asm volatile("s_waitcnt lgkmcnt(0)" ::: "memory")
#define BAR()    asm volatile("s_barrier" ::: "memory")

// ---------------- k_prep: compact | cvt_wfrag | proj_dec fused (R10/R11) -----
__global__ __launch_bounds__(256) void k_prep(const float* __restrict__ W,
                                              const float* __restrict__ dec,
                                              const int* __restrict__ mask,
                                              unsigned short* __restrict__ wf,
                                              float* __restrict__ proj,
                                              int* __restrict__ idx,
                                              int* __restrict__ cntblk) {
    __shared__ int cb[2048];
    __shared__ int cw[4], coff[5];
    const int bx = blockIdx.x, tid = threadIdx.x;
    if (bx < 32) {
        // ---- compact: 4 waves, each scans a 512-token quarter into its slab ----
        const int b = bx, w = tid >> 6, ln = tid & 63;
        const int base = w * 512;
        int cnt = 0;
        for (int r = 0; r < 8; r++) {
            int s = base + r * 64 + ln;
            int m = mask[b * SS + s];
            unsigned long long bal = __ballot(m == 0);
            int pos = __popcll(bal & ((1ull << ln) - 1ull));
            if (m == 0) cb[base + cnt + pos] = s;
            cnt += __popcll(bal);
        }
        if (ln == 0) cw[w] = cnt;
        __syncthreads();
        if (tid == 0) {
            coff[0] = 0;
            for (int q = 0; q < 4; q++) coff[q + 1] = coff[q] + cw[q];
        }
        __syncthreads();
        const int total = coff[4];
        for (int i = tid; i < total; i += 256) {
            int q = (i >= coff[1]) + (i >= coff[2]) + (i >= coff[3]);
            idx[b * SS + i] = cb[q * 512 + (i - coff[q])];
        }
        const int padded = (total + 63) & ~63;
        for (int i = total + tid; i < padded; i += 256) idx[b * SS + i] = (int)0x80000000;
        if (tid == 0) cntblk[b] = padded >> 6;         // chunk count (<=32)
    } else if (bx < 544) {
        // ---- cvt: W_enc fp32 -> bf16 fragment-major (32x32x16 records) ----
        int i = (bx - 32) * 256 + tid;             // 0..131071 (8-elem chunks)
        int d = i >> 7;                            // 0..1023
        int c = i & 127;                           // k-chunk: k = c*8
        const float4* src = (const float4*)(W + (size_t)d * WROW + c * 8);
        float4 a = src[0], b2 = src[1];
        u16x8 o;
        o[0] = f2bf(a.x);  o[1] = f2bf(a.y);  o[2] = f2bf(a.z);  o[3] = f2bf(a.w);
        o[4] = f2bf(b2.x); o[5] = f2bf(b2.y); o[6] = f2bf(b2.z); o[7] = f2bf(b2.w);
        int ks = c >> 1;                           // k>>4
        int l  = (d & 31) + 32 * (c & 1);          // (l>>5) = k-half
        int g  = d >> 5;
        *(u16x8*)(wf + ((size_t)(g * 64 + ks) * 64 + l) * 8) = o;
    } else {
        // ---- proj_dec: W_dec read ONCE total ----
        const int dl = tid >> 6;
        const int b  = (tid >> 1) & 31;
        const int hf = tid & 1;
        const int d  = (bx - 544) * 4 + dl;
        const float* wrow = W + (size_t)d * WROW + HE + hf * 512;
        const float* dv   = dec + b * HD + hf * 512;
        float s = 0.f;
        #pragma unroll 4
        for (int e = 0; e < 512; e += 4) {
            float4 w4 = *(const float4*)(wrow + e);
            float4 x4 = *(const float4*)(dv + e);
            s += w4.x * x4.x + w4.y * x4.y + w4.z * x4.z + w4.w * x4.w;
        }
        s += __shfl_xor(s, 1, 64);
        if (hf == 0) proj[b * HD + d] = s;
    }
}

// ---------------- scores: main (bx<512) + K/d-split tail (bx>=512) -----------
// R12: wall was 3T (2 full rounds + a 3rd round where ~12 CUs work, 244 idle).
// Main path (R11-proven) handles chunks 0..511 = exactly 2 rounds. Excess
// chunks (>=512, ~12) decompose into 8 tail blocks each (one per 128-d slice);
// tail block: 8 waves K-split (wave w = K-tiles 2w,2w+1, wave-local staged),
// LDS atomic f32 reduce (pre-tanh, since tanh needs full-K y), V*tanh partial
// score -> global atomicAdd(scorebuf). k_fixup then does exp/pZ/PV for those
// tokens. Tail block ~= T/8 -> third round collapses ~55us -> ~8us.
__global__ __launch_bounds__(512, 2) void k_scores_mfma8b(
        const float* __restrict__ enc,             // [65536][1024] fp32
        const unsigned short* __restrict__ wf,     // fragment-major bf16 W_enc
        const float* __restrict__ V,
        const float* __restrict__ proj,            // [32][1024]
        const int* __restrict__ idx,               // [32][2048] compacted tokens
        const int* __restrict__ cntblk,            // [32] chunk counts
        float* __restrict__ psc,                   // [65536] p = exp(score)
        float* __restrict__ pZ,                    // [32][32] partial Z
        float* __restrict__ pnum,                  // [32][32][1024] partial ctx num
        float* __restrict__ scorebuf) {            // [65536] pre-zeroed partials
    __shared__ unsigned short SM[32768];           // 64KB: main uses 16KB; tail 8x8KB slabs + 32KB overlay

    const int tid = threadIdx.x;
    const int wv = tid >> 6, ln = tid & 63, l31 = ln & 31, hi = ln >> 5;

    if (blockIdx.x < 512) {
        // ======================= MAIN PATH (R11-proven) =======================
        const int lid = blockIdx.x;
        int b = -1, loc = 0;
        {
            int a = 0;
            #pragma unroll
            for (int i = 0; i < 32; i++) {
                int c = cntblk[i];
                if (lid >= a && lid < a + c) { b = i; loc = lid - a; }
                a += c;
            }
        }
        if (b < 0) return;
        const int lt0 = loc << 6;

        // per-thread A row (K-invariant): gather via compact index
        const int rid = idx[b * SS + lt0 + (tid >> 3)];
        const size_t arow = ((size_t)b * SS + (rid & 0xffff)) * 1024;

        f32x16 acc[2][4];
        #pragma unroll
        for (int m = 0; m < 2; m++)
            #pragma unroll
            for (int n = 0; n < 4; n++)
                #pragma unroll
                for (int r = 0; r < 16; r++) acc[m][n][r] = 0.f;

        float4 areg[2];            // one K-tile of A: 64 rows x 64 k fp32
        bf16x8 bgE[8], bgF[8];     // B frags: [kk*4+n], E = ks 0,1  F = ks 2,3

        #define LOAD_A(k) do { \
            const float4* g_ = (const float4*)(enc + arow + (k) + (tid & 7) * 8); \
            areg[0] = g_[0]; areg[1] = g_[1]; \
        } while (0)

        #define CVTW_A(buf) do { \
            int row_ = tid >> 3; \
            union { u16x8 s; uint4 u; } pk_; \
            pk_.u.x = pk2(areg[0].x, areg[0].y); \
            pk_.u.y = pk2(areg[0].z, areg[0].w); \
            pk_.u.z = pk2(areg[1].x, areg[1].y); \
            pk_.u.w = pk2(areg[1].z, areg[1].w); \
            *(u16x8*)&SM[(buf) * 4096 + row_ * 64 + (((tid & 7) ^ (row_ & 7)) << 3)] = pk_.s; \
        } while (0)

        #define LOADB(bgx, tt, ksb) do { \
            _Pragma("unroll") \
            for (int kk = 0; kk < 2; kk++) \
                _Pragma("unroll") \
                for (int n = 0; n < 4; n++) \
                    bgx[kk * 4 + n] = *(const bf16x8*)(wf + ((size_t)((wv * 4 + n) * 64 + (tt) * 4 + (ksb) + kk) * 64 + ln) * 8); \
            } while (0)

        #define HALF(bg, ksb, Ac) do { \
            _Pragma("unroll") \
            for (int kk = 0; kk < 2; kk++) { \
                bf16x8 af0, af1; \
                { int c_ = ((ksb) + kk) * 2 + hi; int row_ = l31; \
                  af0 = *(const bf16x8*)&(Ac)[row_ * 64 + ((c_ ^ (row_ & 7)) << 3)]; } \
                { int c_ = ((ksb) + kk) * 2 + hi; int row_ = 32 + l31; \
                  af1 = *(const bf16x8*)&(Ac)[row_ * 64 + ((c_ ^ (row_ & 7)) << 3)]; } \
                __builtin_amdgcn_s_setprio(1); \
                _Pragma("unroll") \
                for (int n = 0; n < 4; n++) \
                    acc[0][n] = __builtin_amdgcn_mfma_f32_32x32x16_bf16(af0, bg[kk * 4 + n], acc[0][n], 0, 0, 0); \
                _Pragma("unroll") \
                for (int n = 0; n < 4; n++) \
                    acc[1][n] = __builtin_amdgcn_mfma_f32_32x32x16_bf16(af1, bg[kk * 4 + n], acc[1][n], 0, 0, 0); \
                __builtin_amdgcn_s_setprio(0); \
            } } while (0)

        LOADB(bgE, 0, 0); LOADB(bgF, 0, 2);
        LOAD_A(0);
        CVTW_A(0);
        LOAD_A(64);
        LGKM0(); BAR();

        for (int t = 0; t < 16; ++t) {
            const int cur = t & 1, nxt = cur ^ 1;
            const unsigned short* Ac = SM + cur * 4096;

            HALF(bgE, 0, Ac);
            if (t < 15) {
                LOADB(bgE, t + 1, 0);
                CVTW_A(nxt);
                if (t < 14) LOAD_A((t + 2) * 64);
            }
            HALF(bgF, 2, Ac);
            if (t < 15) {
                LOADB(bgF, t + 1, 2);
                LGKM0(); BAR();
            }
        }
        #undef LOAD_A
        #undef CVTW_A
        #undef LOADB
        #undef HALF

        // ---- fused epilogue: sc[m][r] = sum_n V[d]*tanh(acc + proj) ----
        float sc[2][16];
        #pragma unroll
        for (int m = 0; m < 2; m++)
            #pragma unroll
            for (int r = 0; r < 16; r++) sc[m][r] = 0.f;
        #pragma unroll
        for (int n = 0; n < 4; n++) {
            int d = wv * 128 + n * 32 + l31;
            float pd  = proj[b * 1024 + d];
            float vv  = V[d];
            float vv2 = 2.f * vv;
            #pragma unroll
            for (int m = 0; m < 2; m++)
                #pragma unroll
                for (int r = 0; r < 16; r++) {
                    float y  = acc[m][n][r] + pd;
                    float e2 = __expf(2.f * y);
                    float rc = __builtin_amdgcn_rcpf(e2 + 1.f);
                    sc[m][r] += vv - vv2 * rc;
                }
        }
        #pragma unroll
        for (int m = 0; m < 2; m++)
            #pragma unroll
            for (int r = 0; r < 16; r++) {
                float v = sc[m][r];
                v += __shfl_xor(v, 1, 64);
                v += __shfl_xor(v, 2, 64);
                v += __shfl_xor(v, 4, 64);
                v += __shfl_xor(v, 8, 64);
                v += __shfl_xor(v, 16, 64);
                sc[m][r] = v;
            }

        __syncthreads();
        float* redf = (float*)SM;
        float* pf   = (float*)SM + 512;
        int*   ri   = (int*)SM + 576;
        if (l31 == 0) {
            #pragma unroll
            for (int m = 0; m < 2; m++)
                #pragma unroll
                for (int r = 0; r < 16; r++) {
                    int tok = m * 32 + (r & 3) + 8 * (r >> 2) + 4 * hi;
                    redf[tok * 8 + wv] = sc[m][r];
                }
        }
        __syncthreads();
        if (tid < 64) {
            float s = 0.f;
            #pragma unroll
            for (int w = 0; w < 8; w++) s += redf[tid * 8 + w];
            int sidx = idx[b * SS + lt0 + tid];
            float p = (sidx >= 0) ? __expf(s) : 0.f;
            if (sidx >= 0) psc[b * SS + sidx] = p;
            pf[tid] = p;
            ri[tid] = sidx & 2047;
            float z = p;
            z += __shfl_xor(z, 1, 64);
            z += __shfl_xor(z, 2, 64);
            z += __shfl_xor(z, 4, 64);
            z += __shfl_xor(z, 8, 64);
            z += __shfl_xor(z, 16, 64);
            z += __shfl_xor(z, 32, 64);
            if (tid == 0) pZ[b * 32 + loc] = z;
        }
        __syncthreads();

        float n0 = 0.f, n1 = 0.f;
        const float* encb = enc + (size_t)b * SS * 1024;
        #pragma unroll 8
        for (int s2 = 0; s2 < 64; s2++) {
            float p = pf[s2];
            const float* rp = encb + (size_t)ri[s2] * 1024;
            n0 = fmaf(p, rp[tid], n0);
            n1 = fmaf(p, rp[tid + 512], n1);
        }
        float* pn = pnum + (size_t)(b * 32 + loc) * 1024;
        pn[tid]       = n0;
        pn[tid + 512] = n1;
    } else {
        // ======================= TAIL PATH (excess chunks) ====================
        const int e = blockIdx.x - 512;            // 0..511
        const int dblk = e & 7;                    // 128-d slice
        for (int ex = e >> 3; ex < 512; ex += 64) {
            const int lid = 512 + ex;
            int b = -1, loc = 0;
            {
                int a = 0;
                #pragma unroll
                for (int i = 0; i < 32; i++) {
                    int c = cntblk[i];
                    if (lid >= a && lid < a + c) { b = i; loc = lid - a; }
                    a += c;
                }
            }
            if (b < 0) break;
            const int lt0 = loc << 6;

            f32x16 tacc[2][4];
            #pragma unroll
            for (int m = 0; m < 2; m++)
                #pragma unroll
                for (int n = 0; n < 4; n++)
                    #pragma unroll
                    for (int r = 0; r < 16; r++) tacc[m][n][r] = 0.f;

            unsigned short* slab = SM + 4096 * wv;   // 8KB wave-local
            #pragma unroll
            for (int q = 0; q < 2; q++) {
                const int tt = 2 * wv + q;           // this wave's K-tile
                // stage 64x64 subtile fp32->bf16 (wave-local, XOR-swizzled)
                #pragma unroll
                for (int it = 0; it < 8; it++) {
                    int row = it * 8 + (ln >> 3);
                    int kc  = ln & 7;
                    int r2  = idx[b * SS + lt0 + row];
                    const float4* g_ = (const float4*)(enc +
                        ((size_t)b * SS + (r2 & 0xffff)) * 1024 + tt * 64 + kc * 8);
                    float4 a0 = g_[0], a1 = g_[1];
                    union { u16x8 s; uint4 u; } pk_;
                    pk_.u.x = pk2(a0.x, a0.y); pk_.u.y = pk2(a0.z, a0.w);
                    pk_.u.z = pk2(a1.x, a1.y); pk_.u.w = pk2(a1.z, a1.w);
                    *(u16x8*)&slab[row * 64 + ((kc ^ (row & 7)) << 3)] = pk_.s;
                }
                LGKM0();
                #pragma unroll
                for (int ks = 0; ks < 4; ks++) {
                    bf16x8 bg[4];
                    #pragma unroll
                    for (int n = 0; n < 4; n++)
                        bg[n] = *(const bf16x8*)(wf +
                            ((size_t)((dblk * 4 + n) * 64 + tt * 4 + ks) * 64 + ln) * 8);
                    int c0 = ks * 2 + hi;
                    bf16x8 af0 = *(const bf16x8*)&slab[l31 * 64 + ((c0 ^ (l31 & 7)) << 3)];
                    bf16x8 af1 = *(const bf16x8*)&slab[(32 + l31) * 64 + ((c0 ^ ((32 + l31) & 7)) << 3)];
                    #pragma unroll
                    for (int n = 0; n < 4; n++)
                        tacc[0][n] = __builtin_amdgcn_mfma_f32_32x32x16_bf16(af0, bg[n], tacc[0][n], 0, 0, 0);
                    #pragma unroll
                    for (int n = 0; n < 4; n++)
                        tacc[1][n] = __builtin_amdgcn_mfma_f32_32x32x16_bf16(af1, bg[n], tacc[1][n], 0, 0, 0);
                }
            }
            // reduce 8 waves' partial acc into f32 tile (overlays slabs 0-3)
            BAR();
            float* rt = (float*)SM;                  // [64][128] f32 = 32KB
            for (int i = tid; i < 8192; i += 512) rt[i] = 0.f;
            BAR();
            #pragma unroll
            for (int m = 0; m < 2; m++)
                #pragma unroll
                for (int n = 0; n < 4; n++)
                    #pragma unroll
                    for (int r = 0; r < 16; r++) {
                        int row = m * 32 + (r & 3) + 8 * (r >> 2) + 4 * hi;
                        int col = n * 32 + l31;
                        atomicAdd(&rt[row * 128 + col], tacc[m][n][r]);
                    }
            BAR();
            // partial score over this d-slice -> global atomic
            {
                int tok = tid >> 3, dq = tid & 7;
                float s = 0.f;
                #pragma unroll
                for (int j = 0; j < 16; j++) {
                    int dl = dq * 16 + j;
                    int d  = dblk * 128 + dl;
                    float y  = rt[tok * 128 + dl] + proj[b * 1024 + d];
                    float e2 = __expf(2.f * y);
                    float rc = __builtin_amdgcn_rcpf(e2 + 1.f);
                    s += V[d] * (1.f - 2.f * rc);
                }
                s += __shfl_xor(s, 1, 64);
                s += __shfl_xor(s, 2, 64);
                s += __shfl_xor(s, 4, 64);
                if (dq == 0) {
                    int sidx = idx[b * SS + lt0 + tok];
                    if (sidx >= 0) atomicAdd(&scorebuf[b * SS + sidx], s);
                }
            }
            BAR();   // LDS reuse safety for next excess chunk
        }
    }
}

// ---------------- fixup: exp/pZ/PV for excess chunks (>=512) -----------------
__global__ __launch_bounds__(256) void k_fixup(const float* __restrict__ scorebuf,
                                               const float* __restrict__ enc,
                                               const int* __restrict__ idx,
                                               const int* __restrict__ cntblk,
                                               float* __restrict__ psc,
                                               float* __restrict__ pZ,
                                               float* __restrict__ pnum) {
    __shared__ float pf[64];
    __shared__ int   ri[64];
    const int tid = threadIdx.x;
    for (int ex = blockIdx.x; ex < 512; ex += 64) {
        const int lid = 512 + ex;
        int b = -1, loc = 0;
        {
            int a = 0;
            #pragma unroll
            for (int i = 0; i < 32; i++) {
                int c = cntblk[i];
                if (lid >= a && lid < a + c) { b = i; loc = lid - a; }
                a += c;
            }
        }
        if (b < 0) break;
        const int lt0 = loc << 6;
        if (tid < 64) {
            int sidx = idx[b * SS + lt0 + tid];
            float p = 0.f;
            if (sidx >= 0) {
                p = __expf(scorebuf[b * SS + sidx]);
                psc[b * SS + sidx] = p;
            }
            pf[tid] = p;
            ri[tid] = sidx & 2047;
            float z = p;
            z += __shfl_xor(z, 1, 64);
            z += __shfl_xor(z, 2, 64);
            z += __shfl_xor(z, 4, 64);
            z += __shfl_xor(z, 8, 64);
            z += __shfl_xor(z, 16, 64);
            z += __shfl_xor(z, 32, 64);
            if (tid == 0) pZ[b * 32 + loc] = z;
        }
        __syncthreads();
        float4 acc = {0.f, 0.f, 0.f, 0.f};
        const float4* e4 = (const float4*)(enc + (size_t)b * SS * 1024);
        #pragma unroll 4
        for (int s = 0; s < 64; s++) {
            float p = pf[s];
            float4 v = e4[(size_t)ri[s] * 256 + tid];
            acc.x = fmaf(p, v.x, acc.x); acc.y = fmaf(p, v.y, acc.y);
            acc.z = fmaf(p, v.z, acc.z); acc.w = fmaf(p, v.w, acc.w);
        }
        *(float4*)(pnum + (size_t)(b * 32 + loc) * 1024 + tid * 4) = acc;
        __syncthreads();
    }
}

// ---------------- finish: ctx finalize (bx<128) | attn normalize (bx>=128) ---
__global__ __launch_bounds__(256) void k_finish(const float* __restrict__ pnum,
                                                const float* __restrict__ psc,
                                                const int* __restrict__ mask,
                                                const float* __restrict__ pZ,
                                                const int* __restrict__ cntblk,
                                                float* __restrict__ ctx,
                                                float* __restrict__ attn) {
    const int bx = blockIdx.x, tid = threadIdx.x;
    if (bx < 128) {
        int i = bx * 256 + tid;                   // 0..32767
        int b = i >> 10, e = i & 1023;
        const int c = cntblk[b];
        float Z = 0.f;
        for (int q = 0; q < c; q++) Z += pZ[b * 32 + q];
        float s = 0.f;
        for (int q = 0; q < c; q++) s += pnum[(size_t)(b * 32 + q) * 1024 + e];
        ctx[i] = s / Z;
    } else {
        const int b = bx - 128;
        const int c = cntblk[b];
        float Z = 0.f;
        for (int q = 0; q < c; q++) Z += pZ[b * 32 + q];
        float invZ = 1.f / Z;
        #pragma unroll
        for (int i = 0; i < 8; i++) {
            int s = tid + i * 256;
            int m = mask[b * SS + s];
            float p = m ? 0.f : psc[b * SS + s];
            attn[b * SS + s] = p * invZ;
        }
    }
}

// ================= fp32 fallback (round-0 proven path) =================
__global__ __launch_bounds__(256) void k_projdec2(const float* __restrict__ dec,
                                                  const float* __restrict__ W,
                                                  float* __restrict__ proj) {
    const int tid = threadIdx.x;
    const int dl = tid >> 6;
    const int b  = (tid >> 1) & 31;
    const int hf = tid & 1;
    const int d  = blockIdx.x * 4 + dl;
    const float* wrow = W + (size_t)d * WROW + HE + hf * 512;
    const float* dv   = dec + b * HD + hf * 512;
    float s = 0.f;
    #pragma unroll 4
    for (int e = 0; e < 512; e += 4) {
        float4 w4 = *(const float4*)(wrow + e);
        float4 x4 = *(const float4*)(dv + e);
        s += w4.x * x4.x + w4.y * x4.y + w4.z * x4.z + w4.w * x4.w;
    }
    s += __shfl_xor(s, 1, 64);
    if (hf == 0) proj[b * HD + d] = s;
}

__global__ __launch_bounds__(256) void k_scores_f32(const float* __restrict__ enc,
                                                    const float* __restrict__ W,
                                                    const float* __restrict__ V,
                                                    const float* __restrict__ proj,
                                                    float* __restrict__ scores) {
    __shared__ float As[64][20];
    __shared__ float Bs[64][20];
    __shared__ float red[64][17];
    const int t0 = blockIdx.x * 64;
    const int b  = t0 >> 11;
    const int tid = threadIdx.x;
    const int tx = tid & 15, ty = tid >> 4;
    const int lrow = tid >> 2, lc4 = (tid & 3) * 4;
    float sc[4] = {0.f, 0.f, 0.f, 0.f};
    for (int n0 = 0; n0 < HD; n0 += 64) {
        float C[4][4] = {};
        for (int k0 = 0; k0 < HE; k0 += 16) {
            *(float4*)&As[lrow][lc4] = *(const float4*)(enc + (size_t)(t0 + lrow) * HE + k0 + lc4);
            *(float4*)&Bs[lrow][lc4] = *(const float4*)(W + (size_t)(n0 + lrow) * WROW + k0 + lc4);
            __syncthreads();
            #pragma unroll
            for (int k4 = 0; k4 < 16; k4 += 4) {
                float4 a[4], bb[4];
                #pragma unroll
                for (int i = 0; i < 4; i++) a[i]  = *(float4*)&As[ty * 4 + i][k4];
                #pragma unroll
                for (int j = 0; j < 4; j++) bb[j] = *(float4*)&Bs[tx * 4 + j][k4];
                #pragma unroll
                for (int i = 0; i < 4; i++)
                    #pragma unroll
                    for (int j = 0; j < 4; j++)
                        C[i][j] += a[i].x * bb[j].x + a[i].y * bb[j].y +
                                   a[i].z * bb[j].z + a[i].w * bb[j].w;
            }
            __syncthreads();
        }
        #pragma unroll
        for (int j = 0; j < 4; j++) {
            int d = n0 + tx * 4 + j;
            float pd = proj[b * HD + d];
            float v  = V[d];
            #pragma unroll
            for (int i = 0; i < 4; i++) {
                float y  = C[i][j] + pd;
                float e2 = __expf(2.f * y);
                sc[i] += v * (1.f - 2.f / (e2 + 1.f));
            }
        }
    }
    #pragma unroll
    for (int i = 0; i < 4; i++) red[ty * 4 + i][tx] = sc[i];
    __syncthreads();
    if (tid < 64) {
        float s = 0.f;
        #pragma unroll
        for (int x = 0; x < 16; x++) s += red[tid][x];
        scores[t0 + tid] = s;
    }
}

__global__ __launch_bounds__(256) void k_softmax_f32(float* __restrict__ sc_attn,
                                                     const int* __restrict__ mask) {
    __shared__ float sred[256];
    const int b = blockIdx.x, tid = threadIdx.x;
    float vals[8]; int msk[8];
    float lmax = -1e30f;
    #pragma unroll
    for (int i = 0; i < 8; i++) {
        int s = tid + i * 256;
        vals[i] = sc_attn[b * SS + s];
        msk[i]  = mask[b * SS + s];
        if (!msk[i]) lmax = fmaxf(lmax, vals[i]);
    }
    sred[tid] = lmax; __syncthreads();
    for (int off = 128; off > 0; off >>= 1) {
        if (tid < off) sred[tid] = fmaxf(sred[tid], sred[tid + off]);
        __syncthreads();
    }
    float m = sred[0];
    __syncthreads();
    float ex[8]; float lsum = 0.f;
    #pragma unroll
    for (int i = 0; i < 8; i++) { ex[i] = msk[i] ? 0.f : __expf(vals[i] - m); lsum += ex[i]; }
    sred[tid] = lsum; __syncthreads();
    for (int off = 128; off > 0; off >>= 1) {
        if (tid < off) sred[tid] += sred[tid + off];
        __syncthreads();
    }
    float inv = 1.f / sred[0];
    #pragma unroll
    for (int i = 0; i < 8; i++) sc_attn[b * SS + tid + i * 256] = ex[i] * inv;
}

__global__ __launch_bounds__(256) void k_ctx_atomic(const float* __restrict__ enc,
                                                    const float* __restrict__ attn,
                                                    float* __restrict__ ctx) {
    const int b = blockIdx.x;
    const int e = blockIdx.y * 256 + threadIdx.x;
    const int s0 = blockIdx.z * 256;
    float sum = 0.f;
    for (int s = s0; s < s0 + 256; s++)
        sum += attn[b * SS + s] * enc[((size_t)b * SS + s) * HE + e];
    atomicAdd(&ctx[b * HE + e], sum);
}

extern "C" void kernel_launch(void* const* d_in, const int* in_sizes, int n_in,
                              void* d_out, int out_size, void* d_ws, size_t ws_size,
                              hipStream_t stream) {
    const float* enc  = (const float*)d_in[0];
    const float* dec  = (const float*)d_in[1];
    const int*   mask = (const int*)d_in[2];
    const float* W    = (const float*)d_in[3];
    const float* V    = (const float*)d_in[4];

    float* out  = (float*)d_out;
    float* ctx  = out;               // [32][1024]
    float* attn = out + BB * HE;     // [32][2048]

    // ws: wf 2M | proj 128K | psc 256K | idx 256K | cnt 4K | pZ 4K | pnum 4M | sbuf 256K
    const size_t WF_OFF = 0, PROJ_OFF = 2097152, PSC_OFF = PROJ_OFF + 131072,
                 IDX_OFF = PSC_OFF + 262144, CNT_OFF = IDX_OFF + 262144,
                 PZ_OFF = CNT_OFF + 4096, PN_OFF = PZ_OFF + 4096,
                 SB_OFF = PN_OFF + 4194304, WS_NEED = SB_OFF + 262144;
    if (ws_size >= WS_NEED) {
        char* w = (char*)d_ws;
        unsigned short* wf = (unsigned short*)(w + WF_OFF);
        float* proj        = (float*)(w + PROJ_OFF);
        float* psc         = (float*)(w + PSC_OFF);
        int*   idx         = (int*)(w + IDX_OFF);
        int*   cntblk      = (int*)(w + CNT_OFF);
        float* pZ          = (float*)(w + PZ_OFF);
        float* pnum        = (float*)(w + PN_OFF);
        float* scorebuf    = (float*)(w + SB_OFF);

        hipMemsetAsync(scorebuf, 0, 262144, stream);
        k_prep<<<800, 256, 0, stream>>>(W, dec, mask, wf, proj, idx, cntblk);
        k_scores_mfma8b<<<1024, 512, 0, stream>>>(enc, wf, V, proj, idx, cntblk,
                                                  psc, pZ, pnum, scorebuf);
        k_fixup<<<64, 256, 0, stream>>>(scorebuf, enc, idx, cntblk, psc, pZ, pnum);
        k_finish<<<160, 256, 0, stream>>>(pnum, psc, mask, pZ, cntblk, ctx, attn);
    } else {
        float* proj  = ctx;
        float* score = attn;
        k_projdec2<<<256, 256, 0, stream>>>(dec, W, proj);
        k_scores_f32<<<(BB * SS) / 64, 256, 0, stream>>>(enc, W, V, proj, score);
        k_softmax_f32<<<BB, 256, 0, stream>>>(score, mask);
        hipMemsetAsync(ctx, 0, (size_t)BB * HE * sizeof(float), stream);
        k_ctx_atomic<<<dim3(BB, HE / 256, 8), 256, 0, stream>>>(enc, attn, ctx);
    }
}

// Round 13
// 238.046 us; speedup vs baseline: 1.0202x; 1.0202x over previous
//
#include <hip/hip_runtime.h>
#include <hip/hip_bf16.h>
#include <math.h>

#define BB 32
#define SS 2048
#define HE 1024
#define HD 1024
#define WROW (HE + HD)   // 2048

typedef __attribute__((ext_vector_type(8))) short bf16x8;
typedef __attribute__((ext_vector_type(4))) float f32x4;
typedef __attribute__((ext_vector_type(16))) float f32x16;
typedef __attribute__((ext_vector_type(8))) unsigned short u16x8;

__device__ __forceinline__ unsigned short f2bf(float f) {
    union { float f; unsigned u; } v; v.f = f;
    unsigned r = v.u + 0x7fffu + ((v.u >> 16) & 1u);   // RNE
    return (unsigned short)(r >> 16);
}

__device__ __forceinline__ unsigned int pk2(float x, float y) {
    union { __hip_bfloat162 h; unsigned int u; } c;
    c.h = __float22bfloat162_rn(float2{x, y});          // v_cvt_pk_bf16_f32
    return c.u;
}

#define LGKM0()  asm volatile("s_waitcnt lgkmcnt(0)" ::: "memory")
#define BAR()    asm volatile("s_barrier" ::: "memory")

// ---------------- k_prep: compact | cvt_wfrag | proj_dec fused (R10/R11) -----
// R13: compact section also zeroes scorebuf (removes a memset dispatch).
__global__ __launch_bounds__(256) void k_prep(const float* __restrict__ W,
                                              const float* __restrict__ dec,
                                              const int* __restrict__ mask,
                                              unsigned short* __restrict__ wf,
                                              float* __restrict__ proj,
                                              int* __restrict__ idx,
                                              int* __restrict__ cntblk,
                                              float* __restrict__ scorebuf) {
    __shared__ int cb[2048];
    __shared__ int cw[4], coff[5];
    const int bx = blockIdx.x, tid = threadIdx.x;
    if (bx < 32) {
        // ---- compact: 4 waves, each scans a 512-token quarter into its slab ----
        const int b = bx, w = tid >> 6, ln = tid & 63;
        const int base = w * 512;
        for (int i = tid; i < 2048; i += 256) scorebuf[b * SS + i] = 0.f;
        int cnt = 0;
        for (int r = 0; r < 8; r++) {
            int s = base + r * 64 + ln;
            int m = mask[b * SS + s];
            unsigned long long bal = __ballot(m == 0);
            int pos = __popcll(bal & ((1ull << ln) - 1ull));
            if (m == 0) cb[base + cnt + pos] = s;
            cnt += __popcll(bal);
        }
        if (ln == 0) cw[w] = cnt;
        __syncthreads();
        if (tid == 0) {
            coff[0] = 0;
            for (int q = 0; q < 4; q++) coff[q + 1] = coff[q] + cw[q];
        }
        __syncthreads();
        const int total = coff[4];
        for (int i = tid; i < total; i += 256) {
            int q = (i >= coff[1]) + (i >= coff[2]) + (i >= coff[3]);
            idx[b * SS + i] = cb[q * 512 + (i - coff[q])];
        }
        const int padded = (total + 63) & ~63;
        for (int i = total + tid; i < padded; i += 256) idx[b * SS + i] = (int)0x80000000;
        if (tid == 0) cntblk[b] = padded >> 6;         // chunk count (<=32)
    } else if (bx < 544) {
        // ---- cvt: W_enc fp32 -> bf16 fragment-major (32x32x16 records) ----
        int i = (bx - 32) * 256 + tid;             // 0..131071 (8-elem chunks)
        int d = i >> 7;                            // 0..1023
        int c = i & 127;                           // k-chunk: k = c*8
        const float4* src = (const float4*)(W + (size_t)d * WROW + c * 8);
        float4 a = src[0], b2 = src[1];
        u16x8 o;
        o[0] = f2bf(a.x);  o[1] = f2bf(a.y);  o[2] = f2bf(a.z);  o[3] = f2bf(a.w);
        o[4] = f2bf(b2.x); o[5] = f2bf(b2.y); o[6] = f2bf(b2.z); o[7] = f2bf(b2.w);
        int ks = c >> 1;                           // k>>4
        int l  = (d & 31) + 32 * (c & 1);          // (l>>5) = k-half
        int g  = d >> 5;
        *(u16x8*)(wf + ((size_t)(g * 64 + ks) * 64 + l) * 8) = o;
    } else {
        // ---- proj_dec: W_dec read ONCE total ----
        const int dl = tid >> 6;
        const int b  = (tid >> 1) & 31;
        const int hf = tid & 1;
        const int d  = (bx - 544) * 4 + dl;
        const float* wrow = W + (size_t)d * WROW + HE + hf * 512;
        const float* dv   = dec + b * HD + hf * 512;
        float s = 0.f;
        #pragma unroll 4
        for (int e = 0; e < 512; e += 4) {
            float4 w4 = *(const float4*)(wrow + e);
            float4 x4 = *(const float4*)(dv + e);
            s += w4.x * x4.x + w4.y * x4.y + w4.z * x4.z + w4.w * x4.w;
        }
        s += __shfl_xor(s, 1, 64);
        if (hf == 0) proj[b * HD + d] = s;
    }
}

// ---------------- 8-wave 64x1024 scores + exp + partial Z + fused PV ---------
// R13: byte-exact R11 body, grid 512 -> handles chunks 0..511 in exactly 2
// clean rounds (1 block/CU). Excess chunks go to k_scores_tail (separate
// kernel; R12's merged-kernel packaging degraded this path's codegen/wall).
__global__ __launch_bounds__(512, 2) void k_scores_mfma8b(
        const float* __restrict__ enc,             // [65536][1024] fp32
        const unsigned short* __restrict__ wf,     // fragment-major bf16 W_enc
        const float* __restrict__ V,
        const float* __restrict__ proj,            // [32][1024]
        const int* __restrict__ idx,               // [32][2048] compacted tokens
        const int* __restrict__ cntblk,            // [32] chunk counts
        float* __restrict__ psc,                   // [65536] p = exp(score)
        float* __restrict__ pZ,                    // [32][32] partial Z
        float* __restrict__ pnum) {                // [32][32][1024] partial ctx num
    __shared__ unsigned short SM[8192];            // 16 KB: A dbuf [2][4096]

    const int lid = blockIdx.x;                    // no swizzle (R9: balance fix)
    int b = -1, loc = 0;
    {
        int a = 0;
        #pragma unroll
        for (int i = 0; i < 32; i++) {
            int c = cntblk[i];
            if (lid >= a && lid < a + c) { b = i; loc = lid - a; }
            a += c;
        }
    }
    if (b < 0) return;
    const int lt0 = loc << 6;

    const int tid = threadIdx.x;
    const int wv = tid >> 6, ln = tid & 63, l31 = ln & 31, hi = ln >> 5;

    // per-thread A row (K-invariant): gather via compact index
    const int rid = idx[b * SS + lt0 + (tid >> 3)];
    const size_t arow = ((size_t)b * SS + (rid & 0xffff)) * 1024;

    f32x16 acc[2][4];
    #pragma unroll
    for (int m = 0; m < 2; m++)
        #pragma unroll
        for (int n = 0; n < 4; n++)
            #pragma unroll
            for (int r = 0; r < 16; r++) acc[m][n][r] = 0.f;

    float4 areg[2];            // one K-tile of A: 64 rows x 64 k fp32, 8 fp32/thread
    bf16x8 bgE[8], bgF[8];     // B frags: [kk*4+n], E = ks 0,1  F = ks 2,3

    #define LOAD_A(k) do { \
        const float4* g_ = (const float4*)(enc + arow + (k) + (tid & 7) * 8); \
        areg[0] = g_[0]; areg[1] = g_[1]; \
    } while (0)

    #define CVTW_A(buf) do { \
        int row_ = tid >> 3; \
        union { u16x8 s; uint4 u; } pk_; \
        pk_.u.x = pk2(areg[0].x, areg[0].y); \
        pk_.u.y = pk2(areg[0].z, areg[0].w); \
        pk_.u.z = pk2(areg[1].x, areg[1].y); \
        pk_.u.w = pk2(areg[1].z, areg[1].w); \
        *(u16x8*)&SM[(buf) * 4096 + row_ * 64 + (((tid & 7) ^ (row_ & 7)) << 3)] = pk_.s; \
    } while (0)

    // B record: (g = wv*4 + n)*64 + t*4 + ksabs, lane ln
    #define LOADB(bgx, tt, ksb) do { \
        _Pragma("unroll") \
        for (int kk = 0; kk < 2; kk++) \
            _Pragma("unroll") \
            for (int n = 0; n < 4; n++) \
                bgx[kk * 4 + n] = *(const bf16x8*)(wf + ((size_t)((wv * 4 + n) * 64 + (tt) * 4 + (ksb) + kk) * 64 + ln) * 8); \
        } while (0)

    // one half-K-step (2 ks) of the wave-tile: 4 ds_reads + 16 MFMA
    #define HALF(bg, ksb, Ac) do { \
        _Pragma("unroll") \
        for (int kk = 0; kk < 2; kk++) { \
            bf16x8 af0, af1; \
            { int c_ = ((ksb) + kk) * 2 + hi; int row_ = l31; \
              af0 = *(const bf16x8*)&(Ac)[row_ * 64 + ((c_ ^ (row_ & 7)) << 3)]; } \
            { int c_ = ((ksb) + kk) * 2 + hi; int row_ = 32 + l31; \
              af1 = *(const bf16x8*)&(Ac)[row_ * 64 + ((c_ ^ (row_ & 7)) << 3)]; } \
            __builtin_amdgcn_s_setprio(1); \
            _Pragma("unroll") \
            for (int n = 0; n < 4; n++) \
                acc[0][n] = __builtin_amdgcn_mfma_f32_32x32x16_bf16(af0, bg[kk * 4 + n], acc[0][n], 0, 0, 0); \
            _Pragma("unroll") \
            for (int n = 0; n < 4; n++) \
                acc[1][n] = __builtin_amdgcn_mfma_f32_32x32x16_bf16(af1, bg[kk * 4 + n], acc[1][n], 0, 0, 0); \
            __builtin_amdgcn_s_setprio(0); \
        } } while (0)

    // ---- prologue: bg(0) both halves, A(0)->LDS, A(1) in flight ----
    LOADB(bgE, 0, 0); LOADB(bgF, 0, 2);
    LOAD_A(0);
    CVTW_A(0);                 // compiler waits A(0) loads, leaves bg in flight
    LOAD_A(64);                // A(1)
    LGKM0(); BAR();

    for (int t = 0; t < 16; ++t) {
        const int cur = t & 1, nxt = cur ^ 1;
        const unsigned short* Ac = SM + cur * 4096;

        // ks 0,1
        HALF(bgE, 0, Ac);

        // slot: bgE dead -> reload for t+1; convert A(t+1)->LDS nxt; issue A(t+2)
        if (t < 15) {
            LOADB(bgE, t + 1, 0);
            CVTW_A(nxt);                       // counted vmcnt on areg only
            if (t < 14) LOAD_A((t + 2) * 64);
        }

        // ks 2,3
        HALF(bgF, 2, Ac);

        if (t < 15) {
            LOADB(bgF, t + 1, 2);
            LGKM0(); BAR();                    // A dbuf coherence; B stays in flight
        }
    }
    #undef LOAD_A
    #undef CVTW_A
    #undef LOADB
    #undef HALF

    // ---- fused epilogue: sc[m][r] = sum_n V[d]*tanh(acc + proj) ----
    float sc[2][16];
    #pragma unroll
    for (int m = 0; m < 2; m++)
        #pragma unroll
        for (int r = 0; r < 16; r++) sc[m][r] = 0.f;
    #pragma unroll
    for (int n = 0; n < 4; n++) {
        int d = wv * 128 + n * 32 + l31;
        float pd  = proj[b * 1024 + d];
        float vv  = V[d];
        float vv2 = 2.f * vv;
        #pragma unroll
        for (int m = 0; m < 2; m++)
            #pragma unroll
            for (int r = 0; r < 16; r++) {
                float y  = acc[m][n][r] + pd;
                float e2 = __expf(2.f * y);                 // saturates at +/-inf
                float rc = __builtin_amdgcn_rcpf(e2 + 1.f);
                sc[m][r] += vv - vv2 * rc;                  // vv * tanh(y)
            }
    }

    // butterfly sum over the 32-lane column group (halves independent)
    #pragma unroll
    for (int m = 0; m < 2; m++)
        #pragma unroll
        for (int r = 0; r < 16; r++) {
            float v = sc[m][r];
            v += __shfl_xor(v, 1, 64);
            v += __shfl_xor(v, 2, 64);
            v += __shfl_xor(v, 4, 64);
            v += __shfl_xor(v, 8, 64);
            v += __shfl_xor(v, 16, 64);
            sc[m][r] = v;
        }

    __syncthreads();           // all waves done with LDS; safe to alias
    float* redf = (float*)SM;                  // [64 tok][8 wv] f32 = 2KB
    float* pf   = (float*)SM + 512;            // 64 f32: p per slot
    int*   ri   = (int*)SM + 576;              // 64 ints: local row per slot
    if (l31 == 0) {
        #pragma unroll
        for (int m = 0; m < 2; m++)
            #pragma unroll
            for (int r = 0; r < 16; r++) {
                int tok = m * 32 + (r & 3) + 8 * (r >> 2) + 4 * hi;
                redf[tok * 8 + wv] = sc[m][r];
            }
    }
    __syncthreads();
    if (tid < 64) {
        float s = 0.f;
        #pragma unroll
        for (int w = 0; w < 8; w++) s += redf[tid * 8 + w];
        int sidx = idx[b * SS + lt0 + tid];
        float p = (sidx >= 0) ? __expf(s) : 0.f;   // shift-free softmax: |s|<=51
        if (sidx >= 0) psc[b * SS + sidx] = p;
        pf[tid] = p;
        ri[tid] = sidx & 2047;                     // sentinel -> row 0 (p=0)
        float z = p;
        z += __shfl_xor(z, 1, 64);
        z += __shfl_xor(z, 2, 64);
        z += __shfl_xor(z, 4, 64);
        z += __shfl_xor(z, 8, 64);
        z += __shfl_xor(z, 16, 64);
        z += __shfl_xor(z, 32, 64);
        if (tid == 0) pZ[b * 32 + loc] = z;
    }
    __syncthreads();

    // ---- fused PV: N[e] = sum_s p_s * enc[row_s][e], branch-free, MLP=16 ----
    float n0 = 0.f, n1 = 0.f;
    const float* encb = enc + (size_t)b * SS * 1024;
    #pragma unroll 8
    for (int s2 = 0; s2 < 64; s2++) {
        float p = pf[s2];
        const float* rp = encb + (size_t)ri[s2] * 1024;
        n0 = fmaf(p, rp[tid], n0);
        n1 = fmaf(p, rp[tid + 512], n1);
    }
    float* pn = pnum + (size_t)(b * 32 + loc) * 1024;
    pn[tid]       = n0;
    pn[tid + 512] = n1;
}

// ---------------- tail: K/d-split blocks for excess chunks (>=512) -----------
// Separate kernel (R12's merged-kernel packaging poisoned main codegen; the
// tail math itself passed correctness). ~12 excess chunks x 8 d-slices = ~96
// live blocks, all concurrent -> wall ~ T/8. Wave w computes K-tiles 2w,2w+1
// of a 64tok x 128d slice; 8 partial accs LDS-reduced pre-tanh; V*tanh
// partial score atomicAdd'ed into scorebuf (pre-zeroed by k_prep).
__global__ __launch_bounds__(512, 2) void k_scores_tail(
        const float* __restrict__ enc,
        const unsigned short* __restrict__ wf,
        const float* __restrict__ V,
        const float* __restrict__ proj,
        const int* __restrict__ idx,
        const int* __restrict__ cntblk,
        float* __restrict__ scorebuf) {
    __shared__ unsigned short SM[32768];           // 8x8KB wave slabs; 32KB f32 overlay

    const int tid = threadIdx.x;
    const int wv = tid >> 6, ln = tid & 63, l31 = ln & 31, hi = ln >> 5;
    const int e = blockIdx.x;                      // 0..511
    const int dblk = e & 7;                        // 128-d slice
    for (int ex = e >> 3; ex < 512; ex += 64) {
        const int lid = 512 + ex;
        int b = -1, loc = 0;
        {
            int a = 0;
            #pragma unroll
            for (int i = 0; i < 32; i++) {
                int c = cntblk[i];
                if (lid >= a && lid < a + c) { b = i; loc = lid - a; }
                a += c;
            }
        }
        if (b < 0) break;
        const int lt0 = loc << 6;

        f32x16 tacc[2][4];
        #pragma unroll
        for (int m = 0; m < 2; m++)
            #pragma unroll
            for (int n = 0; n < 4; n++)
                #pragma unroll
                for (int r = 0; r < 16; r++) tacc[m][n][r] = 0.f;

        unsigned short* slab = SM + 4096 * wv;     // 8KB wave-local
        #pragma unroll
        for (int q = 0; q < 2; q++) {
            const int tt = 2 * wv + q;             // this wave's K-tile
            #pragma unroll
            for (int it = 0; it < 8; it++) {
                int row = it * 8 + (ln >> 3);
                int kc  = ln & 7;
                int r2  = idx[b * SS + lt0 + row];
                const float4* g_ = (const float4*)(enc +
                    ((size_t)b * SS + (r2 & 0xffff)) * 1024 + tt * 64 + kc * 8);
                float4 a0 = g_[0], a1 = g_[1];
                union { u16x8 s; uint4 u; } pk_;
                pk_.u.x = pk2(a0.x, a0.y); pk_.u.y = pk2(a0.z, a0.w);
                pk_.u.z = pk2(a1.x, a1.y); pk_.u.w = pk2(a1.z, a1.w);
                *(u16x8*)&slab[row * 64 + ((kc ^ (row & 7)) << 3)] = pk_.s;
            }
            LGKM0();
            #pragma unroll
            for (int ks = 0; ks < 4; ks++) {
                bf16x8 bg[4];
                #pragma unroll
                for (int n = 0; n < 4; n++)
                    bg[n] = *(const bf16x8*)(wf +
                        ((size_t)((dblk * 4 + n) * 64 + tt * 4 + ks) * 64 + ln) * 8);
                int c0 = ks * 2 + hi;
                bf16x8 af0 = *(const bf16x8*)&slab[l31 * 64 + ((c0 ^ (l31 & 7)) << 3)];
                bf16x8 af1 = *(const bf16x8*)&slab[(32 + l31) * 64 + ((c0 ^ ((32 + l31) & 7)) << 3)];
                #pragma unroll
                for (int n = 0; n < 4; n++)
                    tacc[0][n] = __builtin_amdgcn_mfma_f32_32x32x16_bf16(af0, bg[n], tacc[0][n], 0, 0, 0);
                #pragma unroll
                for (int n = 0; n < 4; n++)
                    tacc[1][n] = __builtin_amdgcn_mfma_f32_32x32x16_bf16(af1, bg[n], tacc[1][n], 0, 0, 0);
            }
        }
        // reduce 8 waves' partial acc into f32 tile (overlays slabs 0-3)
        BAR();
        float* rt = (float*)SM;                    // [64][128] f32 = 32KB
        for (int i = tid; i < 8192; i += 512) rt[i] = 0.f;
        BAR();
        #pragma unroll
        for (int m = 0; m < 2; m++)
            #pragma unroll
            for (int n = 0; n < 4; n++)
                #pragma unroll
                for (int r = 0; r < 16; r++) {
                    int row = m * 32 + (r & 3) + 8 * (r >> 2) + 4 * hi;
                    int col = n * 32 + l31;
                    atomicAdd(&rt[row * 128 + col], tacc[m][n][r]);
                }
        BAR();
        // partial score over this d-slice -> global atomic
        {
            int tok = tid >> 3, dq = tid & 7;
            float s = 0.f;
            #pragma unroll
            for (int j = 0; j < 16; j++) {
                int dl = dq * 16 + j;
                int d  = dblk * 128 + dl;
                float y  = rt[tok * 128 + dl] + proj[b * 1024 + d];
                float e2 = __expf(2.f * y);
                float rc = __builtin_amdgcn_rcpf(e2 + 1.f);
                s += V[d] * (1.f - 2.f * rc);
            }
            s += __shfl_xor(s, 1, 64);
            s += __shfl_xor(s, 2, 64);
            s += __shfl_xor(s, 4, 64);
            if (dq == 0) {
                int sidx = idx[b * SS + lt0 + tok];
                if (sidx >= 0) atomicAdd(&scorebuf[b * SS + sidx], s);
            }
        }
        BAR();   // LDS reuse safety for next excess chunk
    }
}

// ---------------- fixup: exp/pZ/PV for excess chunks (>=512) -----------------
__global__ __launch_bounds__(256) void k_fixup(const float* __restrict__ scorebuf,
                                               const float* __restrict__ enc,
                                               const int* __restrict__ idx,
                                               const int* __restrict__ cntblk,
                                               float* __restrict__ psc,
                                               float* __restrict__ pZ,
                                               float* __restrict__ pnum) {
    __shared__ float pf[64];
    __shared__ int   ri[64];
    const int tid = threadIdx.x;
    for (int ex = blockIdx.x; ex < 512; ex += 64) {
        const int lid = 512 + ex;
        int b = -1, loc = 0;
        {
            int a = 0;
            #pragma unroll
            for (int i = 0; i < 32; i++) {
                int c = cntblk[i];
                if (lid >= a && lid < a + c) { b = i; loc = lid - a; }
                a += c;
            }
        }
        if (b < 0) break;
        const int lt0 = loc << 6;
        if (tid < 64) {
            int sidx = idx[b * SS + lt0 + tid];
            float p = 0.f;
            if (sidx >= 0) {
                p = __expf(scorebuf[b * SS + sidx]);
                psc[b * SS + sidx] = p;
            }
            pf[tid] = p;
            ri[tid] = sidx & 2047;
            float z = p;
            z += __shfl_xor(z, 1, 64);
            z += __shfl_xor(z, 2, 64);
            z += __shfl_xor(z, 4, 64);
            z += __shfl_xor(z, 8, 64);
            z += __shfl_xor(z, 16, 64);
            z += __shfl_xor(z, 32, 64);
            if (tid == 0) pZ[b * 32 + loc] = z;
        }
        __syncthreads();
        float4 acc = {0.f, 0.f, 0.f, 0.f};
        const float4* e4 = (const float4*)(enc + (size_t)b * SS * 1024);
        #pragma unroll 4
        for (int s = 0; s < 64; s++) {
            float p = pf[s];
            float4 v = e4[(size_t)ri[s] * 256 + tid];
            acc.x = fmaf(p, v.x, acc.x); acc.y = fmaf(p, v.y, acc.y);
            acc.z = fmaf(p, v.z, acc.z); acc.w = fmaf(p, v.w, acc.w);
        }
        *(float4*)(pnum + (size_t)(b * 32 + loc) * 1024 + tid * 4) = acc;
        __syncthreads();
    }
}

// ---------------- finish: ctx finalize (bx<128) | attn normalize (bx>=128) ---
__global__ __launch_bounds__(256) void k_finish(const float* __restrict__ pnum,
                                                const float* __restrict__ psc,
                                                const int* __restrict__ mask,
                                                const float* __restrict__ pZ,
                                                const int* __restrict__ cntblk,
                                                float* __restrict__ ctx,
                                                float* __restrict__ attn) {
    const int bx = blockIdx.x, tid = threadIdx.x;
    if (bx < 128) {
        int i = bx * 256 + tid;                   // 0..32767
        int b = i >> 10, e = i & 1023;
        const int c = cntblk[b];
        float Z = 0.f;
        for (int q = 0; q < c; q++) Z += pZ[b * 32 + q];
        float s = 0.f;
        for (int q = 0; q < c; q++) s += pnum[(size_t)(b * 32 + q) * 1024 + e];
        ctx[i] = s / Z;
    } else {
        const int b = bx - 128;
        const int c = cntblk[b];
        float Z = 0.f;
        for (int q = 0; q < c; q++) Z += pZ[b * 32 + q];
        float invZ = 1.f / Z;
        #pragma unroll
        for (int i = 0; i < 8; i++) {
            int s = tid + i * 256;
            int m = mask[b * SS + s];
            float p = m ? 0.f : psc[b * SS + s];
            attn[b * SS + s] = p * invZ;
        }
    }
}

// ================= fp32 fallback (round-0 proven path) =================
__global__ __launch_bounds__(256) void k_projdec2(const float* __restrict__ dec,
                                                  const float* __restrict__ W,
                                                  float* __restrict__ proj) {
    const int tid = threadIdx.x;
    const int dl = tid >> 6;
    const int b  = (tid >> 1) & 31;
    const int hf = tid & 1;
    const int d  = blockIdx.x * 4 + dl;
    const float* wrow = W + (size_t)d * WROW + HE + hf * 512;
    const float* dv   = dec + b * HD + hf * 512;
    float s = 0.f;
    #pragma unroll 4
    for (int e = 0; e < 512; e += 4) {
        float4 w4 = *(const float4*)(wrow + e);
        float4 x4 = *(const float4*)(dv + e);
        s += w4.x * x4.x + w4.y * x4.y + w4.z * x4.z + w4.w * x4.w;
    }
    s += __shfl_xor(s, 1, 64);
    if (hf == 0) proj[b * HD + d] = s;
}

__global__ __launch_bounds__(256) void k_scores_f32(const float* __restrict__ enc,
                                                    const float* __restrict__ W,
                                                    const float* __restrict__ V,
                                                    const float* __restrict__ proj,
                                                    float* __restrict__ scores) {
    __shared__ float As[64][20];
    __shared__ float Bs[64][20];
    __shared__ float red[64][17];
    const int t0 = blockIdx.x * 64;
    const int b  = t0 >> 11;
    const int tid = threadIdx.x;
    const int tx = tid & 15, ty = tid >> 4;
    const int lrow = tid >> 2, lc4 = (tid & 3) * 4;
    float sc[4] = {0.f, 0.f, 0.f, 0.f};
    for (int n0 = 0; n0 < HD; n0 += 64) {
        float C[4][4] = {};
        for (int k0 = 0; k0 < HE; k0 += 16) {
            *(float4*)&As[lrow][lc4] = *(const float4*)(enc + (size_t)(t0 + lrow) * HE + k0 + lc4);
            *(float4*)&Bs[lrow][lc4] = *(const float4*)(W + (size_t)(n0 + lrow) * WROW + k0 + lc4);
            __syncthreads();
            #pragma unroll
            for (int k4 = 0; k4 < 16; k4 += 4) {
                float4 a[4], bb[4];
                #pragma unroll
                for (int i = 0; i < 4; i++) a[i]  = *(float4*)&As[ty * 4 + i][k4];
                #pragma unroll
                for (int j = 0; j < 4; j++) bb[j] = *(float4*)&Bs[tx * 4 + j][k4];
                #pragma unroll
                for (int i = 0; i < 4; i++)
                    #pragma unroll
                    for (int j = 0; j < 4; j++)
                        C[i][j] += a[i].x * bb[j].x + a[i].y * bb[j].y +
                                   a[i].z * bb[j].z + a[i].w * bb[j].w;
            }
            __syncthreads();
        }
        #pragma unroll
        for (int j = 0; j < 4; j++) {
            int d = n0 + tx * 4 + j;
            float pd = proj[b * HD + d];
            float v  = V[d];
            #pragma unroll
            for (int i = 0; i < 4; i++) {
                float y  = C[i][j] + pd;
                float e2 = __expf(2.f * y);
                sc[i] += v * (1.f - 2.f / (e2 + 1.f));
            }
        }
    }
    #pragma unroll
    for (int i = 0; i < 4; i++) red[ty * 4 + i][tx] = sc[i];
    __syncthreads();
    if (tid < 64) {
        float s = 0.f;
        #pragma unroll
        for (int x = 0; x < 16; x++) s += red[tid][x];
        scores[t0 + tid] = s;
    }
}

__global__ __launch_bounds__(256) void k_softmax_f32(float* __restrict__ sc_attn,
                                                     const int* __restrict__ mask) {
    __shared__ float sred[256];
    const int b = blockIdx.x, tid = threadIdx.x;
    float vals[8]; int msk[8];
    float lmax = -1e30f;
    #pragma unroll
    for (int i = 0; i < 8; i++) {
        int s = tid + i * 256;
        vals[i] = sc_attn[b * SS + s];
        msk[i]  = mask[b * SS + s];
        if (!msk[i]) lmax = fmaxf(lmax, vals[i]);
    }
    sred[tid] = lmax; __syncthreads();
    for (int off = 128; off > 0; off >>= 1) {
        if (tid < off) sred[tid] = fmaxf(sred[tid], sred[tid + off]);
        __syncthreads();
    }
    float m = sred[0];
    __syncthreads();
    float ex[8]; float lsum = 0.f;
    #pragma unroll
    for (int i = 0; i < 8; i++) { ex[i] = msk[i] ? 0.f : __expf(vals[i] - m); lsum += ex[i]; }
    sred[tid] = lsum; __syncthreads();
    for (int off = 128; off > 0; off >>= 1) {
        if (tid < off) sred[tid] += sred[tid + off];
        __syncthreads();
    }
    float inv = 1.f / sred[0];
    #pragma unroll
    for (int i = 0; i < 8; i++) sc_attn[b * SS + tid + i * 256] = ex[i] * inv;
}

__global__ __launch_bounds__(256) void k_ctx_atomic(const float* __restrict__ enc,
                                                    const float* __restrict__ attn,
                                                    float* __restrict__ ctx) {
    const int b = blockIdx.x;
    const int e = blockIdx.y * 256 + threadIdx.x;
    const int s0 = blockIdx.z * 256;
    float sum = 0.f;
    for (int s = s0; s < s0 + 256; s++)
        sum += attn[b * SS + s] * enc[((size_t)b * SS + s) * HE + e];
    atomicAdd(&ctx[b * HE + e], sum);
}

extern "C" void kernel_launch(void* const* d_in, const int* in_sizes, int n_in,
                              void* d_out, int out_size, void* d_ws, size_t ws_size,
                              hipStream_t stream) {
    const float* enc  = (const float*)d_in[0];
    const float* dec  = (const float*)d_in[1];
    const int*   mask = (const int*)d_in[2];
    const float* W    = (const float*)d_in[3];
    const float* V    = (const float*)d_in[4];

    float* out  = (float*)d_out;
    float* ctx  = out;               // [32][1024]
    float* attn = out + BB * HE;     // [32][2048]

    // ws: wf 2M | proj 128K | psc 256K | idx 256K | cnt 4K | pZ 4K | pnum 4M | sbuf 256K
    const size_t WF_OFF = 0, PROJ_OFF = 2097152, PSC_OFF = PROJ_OFF + 131072,
                 IDX_OFF = PSC_OFF + 262144, CNT_OFF = IDX_OFF + 262144,
                 PZ_OFF = CNT_OFF + 4096, PN_OFF = PZ_OFF + 4096,
                 SB_OFF = PN_OFF + 4194304, WS_NEED = SB_OFF + 262144;
    if (ws_size >= WS_NEED) {
        char* w = (char*)d_ws;
        unsigned short* wf = (unsigned short*)(w + WF_OFF);
        float* proj        = (float*)(w + PROJ_OFF);
        float* psc         = (float*)(w + PSC_OFF);
        int*   idx         = (int*)(w + IDX_OFF);
        int*   cntblk      = (int*)(w + CNT_OFF);
        float* pZ          = (float*)(w + PZ_OFF);
        float* pnum        = (float*)(w + PN_OFF);
        float* scorebuf    = (float*)(w + SB_OFF);

        k_prep<<<800, 256, 0, stream>>>(W, dec, mask, wf, proj, idx, cntblk, scorebuf);
        k_scores_mfma8b<<<512, 512, 0, stream>>>(enc, wf, V, proj, idx, cntblk,
                                                 psc, pZ, pnum);
        k_scores_tail<<<512, 512, 0, stream>>>(enc, wf, V, proj, idx, cntblk, scorebuf);
        k_fixup<<<64, 256, 0, stream>>>(scorebuf, enc, idx, cntblk, psc, pZ, pnum);
        k_finish<<<160, 256, 0, stream>>>(pnum, psc, mask, pZ, cntblk, ctx, attn);
    } else {
        float* proj  = ctx;
        float* score = attn;
        k_projdec2<<<256, 256, 0, stream>>>(dec, W, proj);
        k_scores_f32<<<(BB * SS) / 64, 256, 0, stream>>>(enc, W, V, proj, score);
        k_softmax_f32<<<BB, 256, 0, stream>>>(score, mask);
        hipMemsetAsync(ctx, 0, (size_t)BB * HE * sizeof(float), stream);
        k_ctx_atomic<<<dim3(BB, HE / 256, 8), 256, 0, stream>>>(enc, attn, ctx);
    }
}

// Round 14
// 176.204 us; speedup vs baseline: 1.3783x; 1.3510x over previous
//
#include <hip/hip_runtime.h>
#include <hip/hip_bf16.h>
#include <math.h>

#define BB 32
#define SS 2048
#define HE 1024
#define HD 1024
#define WROW (HE + HD)   // 2048

typedef __attribute__((ext_vector_type(8))) short bf16x8;
typedef __attribute__((ext_vector_type(4))) float f32x4;
typedef __attribute__((ext_vector_type(16))) float f32x16;
typedef __attribute__((ext_vector_type(8))) unsigned short u16x8;

__device__ __forceinline__ unsigned short f2bf(float f) {
    union { float f; unsigned u; } v; v.f = f;
    unsigned r = v.u + 0x7fffu + ((v.u >> 16) & 1u);   // RNE
    return (unsigned short)(r >> 16);
}

__device__ __forceinline__ unsigned int pk2(float x, float y) {
    union { __hip_bfloat162 h; unsigned int u; } c;
    c.h = __float22bfloat162_rn(float2{x, y});          // v_cvt_pk_bf16_f32
    return c.u;
}

#define LGKM0()  asm volatile("s_waitcnt lgkmcnt(0)" ::: "memory")
#define BAR()    asm volatile("s_barrier" ::: "memory")

// ---------------- k_prep: compact | cvt_wfrag | proj_dec fused ----------------
// R14: compact is UNPADDED (live count per batch, no sentinels). Global chunking
// happens in the scores kernel via prefix over cnt[]. b==0 block zeroes Zg.
__global__ __launch_bounds__(256) void k_prep(const float* __restrict__ W,
                                              const float* __restrict__ dec,
                                              const int* __restrict__ mask,
                                              unsigned short* __restrict__ wf,
                                              float* __restrict__ proj,
                                              int* __restrict__ idx,
                                              int* __restrict__ cnt,
                                              float* __restrict__ Zg) {
    __shared__ int cb[2048];
    __shared__ int cw[4], coff[5];
    const int bx = blockIdx.x, tid = threadIdx.x;
    if (bx < 32) {
        // ---- compact: 4 waves, each scans a 512-token quarter into its slab ----
        const int b = bx, w = tid >> 6, ln = tid & 63;
        const int base = w * 512;
        if (b == 0 && tid < 32) Zg[tid] = 0.f;
        int cntw = 0;
        for (int r = 0; r < 8; r++) {
            int s = base + r * 64 + ln;
            int m = mask[b * SS + s];
            unsigned long long bal = __ballot(m == 0);
            int pos = __popcll(bal & ((1ull << ln) - 1ull));
            if (m == 0) cb[base + cntw + pos] = s;
            cntw += __popcll(bal);
        }
        if (ln == 0) cw[w] = cntw;
        __syncthreads();
        if (tid == 0) {
            coff[0] = 0;
            for (int q = 0; q < 4; q++) coff[q + 1] = coff[q] + cw[q];
        }
        __syncthreads();
        const int total = coff[4];
        for (int i = tid; i < total; i += 256) {
            int q = (i >= coff[1]) + (i >= coff[2]) + (i >= coff[3]);
            idx[b * SS + i] = cb[q * 512 + (i - coff[q])];
        }
        if (tid == 0) cnt[b] = total;              // LIVE count (unpadded)
    } else if (bx < 544) {
        // ---- cvt: W_enc fp32 -> bf16 fragment-major (32x32x16 records) ----
        int i = (bx - 32) * 256 + tid;             // 0..131071 (8-elem chunks)
        int d = i >> 7;                            // 0..1023
        int c = i & 127;                           // k-chunk: k = c*8
        const float4* src = (const float4*)(W + (size_t)d * WROW + c * 8);
        float4 a = src[0], b2 = src[1];
        u16x8 o;
        o[0] = f2bf(a.x);  o[1] = f2bf(a.y);  o[2] = f2bf(a.z);  o[3] = f2bf(a.w);
        o[4] = f2bf(b2.x); o[5] = f2bf(b2.y); o[6] = f2bf(b2.z); o[7] = f2bf(b2.w);
        int ks = c >> 1;                           // k>>4
        int l  = (d & 31) + 32 * (c & 1);          // (l>>5) = k-half
        int g  = d >> 5;
        *(u16x8*)(wf + ((size_t)(g * 64 + ks) * 64 + l) * 8) = o;
    } else {
        // ---- proj_dec: W_dec read ONCE total ----
        const int dl = tid >> 6;
        const int b  = (tid >> 1) & 31;
        const int hf = tid & 1;
        const int d  = (bx - 544) * 4 + dl;
        const float* wrow = W + (size_t)d * WROW + HE + hf * 512;
        const float* dv   = dec + b * HD + hf * 512;
        float s = 0.f;
        #pragma unroll 4
        for (int e = 0; e < 512; e += 4) {
            float4 w4 = *(const float4*)(wrow + e);
            float4 x4 = *(const float4*)(dv + e);
            s += w4.x * x4.x + w4.y * x4.y + w4.z * x4.z + w4.w * x4.w;
        }
        s += __shfl_xor(s, 1, 64);
        if (hf == 0) proj[b * HD + d] = s;
    }
}

// ---------------- 8-wave 64x1024 scores + exp + Z + fused PV, GLOBAL chunks --
// R14: block g handles 64 consecutive tokens of the GLOBAL (cross-batch)
// compact list -> ceil(T_live/64) ~ 508 chunks <= 512 = exactly 2 clean
// rounds at 1 block/CU (kills R11's 3rd-round straggler; Sum ceil(live_b/64)
// per-batch padding gave 524). A chunk spans <=2 batches (live_b ~ 1024 >>
// 64): per-chunk ballot mask selects per-token proj (pd_lo/pd_hi), Z is
// segment-reduced into global Zg[32] (2 atomics/chunk), PV writes dual-slot
// partials pnum[g][2][1024]. MFMA core/schedule byte-identical to R11.
__global__ __launch_bounds__(512, 2) void k_scores_mfma8b(
        const float* __restrict__ enc,             // [65536][1024] fp32
        const unsigned short* __restrict__ wf,     // fragment-major bf16 W_enc
        const float* __restrict__ V,
        const float* __restrict__ proj,            // [32][1024]
        const int* __restrict__ idx,               // [32][2048] per-batch compact
        const int* __restrict__ cnt,               // [32] live counts
        float* __restrict__ psc,                   // [65536] p = exp(score)
        float* __restrict__ Zg,                    // [32] global Z (atomic)
        float* __restrict__ pnum) {                // [chunks][2][1024] PV partials
    __shared__ unsigned short SM[8192];            // 16 KB: A dbuf [2][4096]

    const int g = blockIdx.x;
    const int tid = threadIdx.x;
    const int wv = tid >> 6, ln = tid & 63, l31 = ln & 31, hi = ln >> 5;

    // per-thread global-position scan: slot j = tid>>3, P = g*64+j
    size_t arow;
    {
        const int P = g * 64 + (tid >> 3);
        int total = 0, bj = -1, offj = 0;
        #pragma unroll
        for (int i = 0; i < 32; i++) {
            int c = cnt[i];
            if (P >= total && P < total + c) { bj = i; offj = total; }
            total += c;
        }
        if (g * 64 >= total) return;               // dead block (g >= chunks)
        size_t rowid = 0;
        if (bj >= 0) rowid = (size_t)bj * SS + idx[bj * SS + (P - offj)];
        arow = rowid * 1024;
    }

    f32x16 acc[2][4];
    #pragma unroll
    for (int m = 0; m < 2; m++)
        #pragma unroll
        for (int n = 0; n < 4; n++)
            #pragma unroll
            for (int r = 0; r < 16; r++) acc[m][n][r] = 0.f;

    float4 areg[2];            // one K-tile of A: 64 rows x 64 k fp32, 8 fp32/thread
    bf16x8 bgE[8], bgF[8];     // B frags: [kk*4+n], E = ks 0,1  F = ks 2,3

    #define LOAD_A(k) do { \
        const float4* g_ = (const float4*)(enc + arow + (k) + (tid & 7) * 8); \
        areg[0] = g_[0]; areg[1] = g_[1]; \
    } while (0)

    #define CVTW_A(buf) do { \
        int row_ = tid >> 3; \
        union { u16x8 s; uint4 u; } pk_; \
        pk_.u.x = pk2(areg[0].x, areg[0].y); \
        pk_.u.y = pk2(areg[0].z, areg[0].w); \
        pk_.u.z = pk2(areg[1].x, areg[1].y); \
        pk_.u.w = pk2(areg[1].z, areg[1].w); \
        *(u16x8*)&SM[(buf) * 4096 + row_ * 64 + (((tid & 7) ^ (row_ & 7)) << 3)] = pk_.s; \
    } while (0)

    // B record: (g2 = wv*4 + n)*64 + t*4 + ksabs, lane ln
    #define LOADB(bgx, tt, ksb) do { \
        _Pragma("unroll") \
        for (int kk = 0; kk < 2; kk++) \
            _Pragma("unroll") \
            for (int n = 0; n < 4; n++) \
                bgx[kk * 4 + n] = *(const bf16x8*)(wf + ((size_t)((wv * 4 + n) * 64 + (tt) * 4 + (ksb) + kk) * 64 + ln) * 8); \
        } while (0)

    // one half-K-step (2 ks) of the wave-tile: 4 ds_reads + 16 MFMA
    #define HALF(bg, ksb, Ac) do { \
        _Pragma("unroll") \
        for (int kk = 0; kk < 2; kk++) { \
            bf16x8 af0, af1; \
            { int c_ = ((ksb) + kk) * 2 + hi; int row_ = l31; \
              af0 = *(const bf16x8*)&(Ac)[row_ * 64 + ((c_ ^ (row_ & 7)) << 3)]; } \
            { int c_ = ((ksb) + kk) * 2 + hi; int row_ = 32 + l31; \
              af1 = *(const bf16x8*)&(Ac)[row_ * 64 + ((c_ ^ (row_ & 7)) << 3)]; } \
            __builtin_amdgcn_s_setprio(1); \
            _Pragma("unroll") \
            for (int n = 0; n < 4; n++) \
                acc[0][n] = __builtin_amdgcn_mfma_f32_32x32x16_bf16(af0, bg[kk * 4 + n], acc[0][n], 0, 0, 0); \
            _Pragma("unroll") \
            for (int n = 0; n < 4; n++) \
                acc[1][n] = __builtin_amdgcn_mfma_f32_32x32x16_bf16(af1, bg[kk * 4 + n], acc[1][n], 0, 0, 0); \
            __builtin_amdgcn_s_setprio(0); \
        } } while (0)

    // ---- prologue: bg(0) both halves, A(0)->LDS, A(1) in flight ----
    LOADB(bgE, 0, 0); LOADB(bgF, 0, 2);
    LOAD_A(0);
    CVTW_A(0);                 // compiler waits A(0) loads, leaves bg in flight
    LOAD_A(64);                // A(1)
    LGKM0(); BAR();

    for (int t = 0; t < 16; ++t) {
        const int cur = t & 1, nxt = cur ^ 1;
        const unsigned short* Ac = SM + cur * 4096;

        // ks 0,1
        HALF(bgE, 0, Ac);

        // slot: bgE dead -> reload for t+1; convert A(t+1)->LDS nxt; issue A(t+2)
        if (t < 15) {
            LOADB(bgE, t + 1, 0);
            CVTW_A(nxt);                       // counted vmcnt on areg only
            if (t < 14) LOAD_A((t + 2) * 64);
        }

        // ks 2,3
        HALF(bgF, 2, Ac);

        if (t < 15) {
            LOADB(bgF, t + 1, 2);
            LGKM0(); BAR();                    // A dbuf coherence; B stays in flight
        }
    }
    #undef LOAD_A
    #undef CVTW_A
    #undef LOADB
    #undef HALF

    // ---- chunk mapping tables (before tanh epilogue: pd needs batch select) --
    __syncthreads();           // all waves done with LDS dbuf; safe to alias
    float* redf = (float*)SM;                  // [64 tok][8 wv] f32 = 2KB
    float* pf   = (float*)SM + 512;            // 64 f32: p per slot
    int*   ri   = (int*)SM + 576;              // 64 ints: GLOBAL row per slot
    int*   meta = (int*)SM + 640;              // [0]=blo [1]=bhi [2,3]=ballot mask
    int*   lv   = (int*)SM + 644;              // 64 ints: live flag
    if (tid < 64) {
        const int P = g * 64 + tid;
        int total = 0, b2 = -1, off2 = 0;
        #pragma unroll
        for (int i = 0; i < 32; i++) {
            int c = cnt[i];
            if (P >= total && P < total + c) { b2 = i; off2 = total; }
            total += c;
        }
        int live = (b2 >= 0);
        int row2 = live ? (b2 * SS + idx[b2 * SS + (P - off2)]) : 0;
        ri[tid] = row2;
        lv[tid] = live;
        int blo = __shfl(b2, 0, 64);
        int bhr = __shfl(b2, 63, 64);
        int bhi = (bhr < 0) ? blo : bhr;
        unsigned long long bm = __ballot(live && b2 == bhi && bhi != blo);
        if (tid == 0) {
            meta[0] = blo; meta[1] = bhi;
            meta[2] = (int)(unsigned)(bm & 0xffffffffull);
            meta[3] = (int)(unsigned)(bm >> 32);
        }
    }
    __syncthreads();
    const int blo = meta[0], bhi = meta[1];
    const unsigned long long bm =
        ((unsigned long long)(unsigned)meta[3] << 32) | (unsigned)meta[2];

    // ---- fused epilogue: sc[m][r] = sum_n V[d]*tanh(acc + proj_sel) ----
    float sc[2][16];
    #pragma unroll
    for (int m = 0; m < 2; m++)
        #pragma unroll
        for (int r = 0; r < 16; r++) sc[m][r] = 0.f;
    #pragma unroll
    for (int n = 0; n < 4; n++) {
        int d = wv * 128 + n * 32 + l31;
        float pdl = proj[blo * 1024 + d];
        float pdh = proj[bhi * 1024 + d];
        float vv  = V[d];
        float vv2 = 2.f * vv;
        #pragma unroll
        for (int m = 0; m < 2; m++)
            #pragma unroll
            for (int r = 0; r < 16; r++) {
                int tok = m * 32 + (r & 3) + 8 * (r >> 2) + 4 * hi;
                float pd = ((bm >> tok) & 1ull) ? pdh : pdl;
                float y  = acc[m][n][r] + pd;
                float e2 = __expf(2.f * y);                 // saturates at +/-inf
                float rc = __builtin_amdgcn_rcpf(e2 + 1.f);
                sc[m][r] += vv - vv2 * rc;                  // vv * tanh(y)
            }
    }

    // butterfly sum over the 32-lane column group (halves independent)
    #pragma unroll
    for (int m = 0; m < 2; m++)
        #pragma unroll
        for (int r = 0; r < 16; r++) {
            float v = sc[m][r];
            v += __shfl_xor(v, 1, 64);
            v += __shfl_xor(v, 2, 64);
            v += __shfl_xor(v, 4, 64);
            v += __shfl_xor(v, 8, 64);
            v += __shfl_xor(v, 16, 64);
            sc[m][r] = v;
        }

    if (l31 == 0) {
        #pragma unroll
        for (int m = 0; m < 2; m++)
            #pragma unroll
            for (int r = 0; r < 16; r++) {
                int tok = m * 32 + (r & 3) + 8 * (r >> 2) + 4 * hi;
                redf[tok * 8 + wv] = sc[m][r];
            }
    }
    __syncthreads();
    if (tid < 64) {
        float s = 0.f;
        #pragma unroll
        for (int w = 0; w < 8; w++) s += redf[tid * 8 + w];
        int live = lv[tid];
        float p = live ? __expf(s) : 0.f;          // shift-free softmax: |s|<=51
        if (live) psc[ri[tid]] = p;
        pf[tid] = p;
        int selh = (int)((bm >> tid) & 1ull);
        float zh = selh ? p : 0.f;
        float zl = p - zh;
        #pragma unroll
        for (int o = 1; o < 64; o <<= 1) {
            zl += __shfl_xor(zl, o, 64);
            zh += __shfl_xor(zh, o, 64);
        }
        if (tid == 0) {
            atomicAdd(&Zg[blo], zl);
            if (bhi != blo) atomicAdd(&Zg[bhi], zh);
        }
    }
    __syncthreads();

    // ---- fused PV: dual-slot N[e] = sum_s p_s * enc[row_s][e] ----
    float n0l = 0.f, n1l = 0.f, n0h = 0.f, n1h = 0.f;
    #pragma unroll 8
    for (int s2 = 0; s2 < 64; s2++) {
        float p  = pf[s2];
        float ph = ((bm >> s2) & 1ull) ? p : 0.f;
        float pl = p - ph;
        const float* rp = enc + (size_t)ri[s2] * 1024;
        float v0 = rp[tid], v1 = rp[tid + 512];
        n0l = fmaf(pl, v0, n0l);
        n1l = fmaf(pl, v1, n1l);
        n0h = fmaf(ph, v0, n0h);
        n1h = fmaf(ph, v1, n1h);
    }
    float* pn = pnum + (size_t)g * 2048;
    pn[tid]        = n0l;
    pn[tid + 512]  = n1l;
    pn[tid + 1024] = n0h;
    pn[tid + 1536] = n1h;
}

// ---------------- finish: ctx finalize (bx<128) | attn normalize (bx>=128) ---
// ctx[b][e] = (sum over batch b's contiguous chunk range, slot 1 for the
// leading boundary chunk, slot 0 otherwise) / Zg[b].
__global__ __launch_bounds__(256) void k_finish(const float* __restrict__ pnum,
                                                const float* __restrict__ psc,
                                                const int* __restrict__ mask,
                                                const float* __restrict__ Zg,
                                                const int* __restrict__ cnt,
                                                float* __restrict__ ctx,
                                                float* __restrict__ attn) {
    const int bx = blockIdx.x, tid = threadIdx.x;
    if (bx < 128) {
        int i = bx * 256 + tid;                   // 0..32767
        int b = i >> 10, e = i & 1023;
        int off = 0;
        for (int q = 0; q < b; q++) off += cnt[q];
        const int cb = cnt[b];
        const int c0 = off >> 6, c1 = (off + cb - 1) >> 6;
        float s = 0.f;
        for (int c = c0; c <= c1; c++) {
            int slot = (c == c0 && (off & 63)) ? 1 : 0;
            s += pnum[(size_t)c * 2048 + slot * 1024 + e];
        }
        ctx[i] = s / Zg[b];
    } else {
        const int b = bx - 128;
        float invZ = 1.f / Zg[b];
        #pragma unroll
        for (int i = 0; i < 8; i++) {
            int s = tid + i * 256;
            int m = mask[b * SS + s];
            float p = m ? 0.f : psc[b * SS + s];
            attn[b * SS + s] = p * invZ;
        }
    }
}

// ================= fp32 fallback (round-0 proven path) =================
__global__ __launch_bounds__(256) void k_projdec2(const float* __restrict__ dec,
                                                  const float* __restrict__ W,
                                                  float* __restrict__ proj) {
    const int tid = threadIdx.x;
    const int dl = tid >> 6;
    const int b  = (tid >> 1) & 31;
    const int hf = tid & 1;
    const int d  = blockIdx.x * 4 + dl;
    const float* wrow = W + (size_t)d * WROW + HE + hf * 512;
    const float* dv   = dec + b * HD + hf * 512;
    float s = 0.f;
    #pragma unroll 4
    for (int e = 0; e < 512; e += 4) {
        float4 w4 = *(const float4*)(wrow + e);
        float4 x4 = *(const float4*)(dv + e);
        s += w4.x * x4.x + w4.y * x4.y + w4.z * x4.z + w4.w * x4.w;
    }
    s += __shfl_xor(s, 1, 64);
    if (hf == 0) proj[b * HD + d] = s;
}

__global__ __launch_bounds__(256) void k_scores_f32(const float* __restrict__ enc,
                                                    const float* __restrict__ W,
                                                    const float* __restrict__ V,
                                                    const float* __restrict__ proj,
                                                    float* __restrict__ scores) {
    __shared__ float As[64][20];
    __shared__ float Bs[64][20];
    __shared__ float red[64][17];
    const int t0 = blockIdx.x * 64;
    const int b  = t0 >> 11;
    const int tid = threadIdx.x;
    const int tx = tid & 15, ty = tid >> 4;
    const int lrow = tid >> 2, lc4 = (tid & 3) * 4;
    float sc[4] = {0.f, 0.f, 0.f, 0.f};
    for (int n0 = 0; n0 < HD; n0 += 64) {
        float C[4][4] = {};
        for (int k0 = 0; k0 < HE; k0 += 16) {
            *(float4*)&As[lrow][lc4] = *(const float4*)(enc + (size_t)(t0 + lrow) * HE + k0 + lc4);
            *(float4*)&Bs[lrow][lc4] = *(const float4*)(W + (size_t)(n0 + lrow) * WROW + k0 + lc4);
            __syncthreads();
            #pragma unroll
            for (int k4 = 0; k4 < 16; k4 += 4) {
                float4 a[4], bb[4];
                #pragma unroll
                for (int i = 0; i < 4; i++) a[i]  = *(float4*)&As[ty * 4 + i][k4];
                #pragma unroll
                for (int j = 0; j < 4; j++) bb[j] = *(float4*)&Bs[tx * 4 + j][k4];
                #pragma unroll
                for (int i = 0; i < 4; i++)
                    #pragma unroll
                    for (int j = 0; j < 4; j++)
                        C[i][j] += a[i].x * bb[j].x + a[i].y * bb[j].y +
                                   a[i].z * bb[j].z + a[i].w * bb[j].w;
            }
            __syncthreads();
        }
        #pragma unroll
        for (int j = 0; j < 4; j++) {
            int d = n0 + tx * 4 + j;
            float pd = proj[b * HD + d];
            float v  = V[d];
            #pragma unroll
            for (int i = 0; i < 4; i++) {
                float y  = C[i][j] + pd;
                float e2 = __expf(2.f * y);
                sc[i] += v * (1.f - 2.f / (e2 + 1.f));
            }
        }
    }
    #pragma unroll
    for (int i = 0; i < 4; i++) red[ty * 4 + i][tx] = sc[i];
    __syncthreads();
    if (tid < 64) {
        float s = 0.f;
        #pragma unroll
        for (int x = 0; x < 16; x++) s += red[tid][x];
        scores[t0 + tid] = s;
    }
}

__global__ __launch_bounds__(256) void k_softmax_f32(float* __restrict__ sc_attn,
                                                     const int* __restrict__ mask) {
    __shared__ float sred[256];
    const int b = blockIdx.x, tid = threadIdx.x;
    float vals[8]; int msk[8];
    float lmax = -1e30f;
    #pragma unroll
    for (int i = 0; i < 8; i++) {
        int s = tid + i * 256;
        vals[i] = sc_attn[b * SS + s];
        msk[i]  = mask[b * SS + s];
        if (!msk[i]) lmax = fmaxf(lmax, vals[i]);
    }
    sred[tid] = lmax; __syncthreads();
    for (int off = 128; off > 0; off >>= 1) {
        if (tid < off) sred[tid] = fmaxf(sred[tid], sred[tid + off]);
        __syncthreads();
    }
    float m = sred[0];
    __syncthreads();
    float ex[8]; float lsum = 0.f;
    #pragma unroll
    for (int i = 0; i < 8; i++) { ex[i] = msk[i] ? 0.f : __expf(vals[i] - m); lsum += ex[i]; }
    sred[tid] = lsum; __syncthreads();
    for (int off = 128; off > 0; off >>= 1) {
        if (tid < off) sred[tid] += sred[tid + off];
        __syncthreads();
    }
    float inv = 1.f / sred[0];
    #pragma unroll
    for (int i = 0; i < 8; i++) sc_attn[b * SS + tid + i * 256] = ex[i] * inv;
}

__global__ __launch_bounds__(256) void k_ctx_atomic(const float* __restrict__ enc,
                                                    const float* __restrict__ attn,
                                                    float* __restrict__ ctx) {
    const int b = blockIdx.x;
    const int e = blockIdx.y * 256 + threadIdx.x;
    const int s0 = blockIdx.z * 256;
    float sum = 0.f;
    for (int s = s0; s < s0 + 256; s++)
        sum += attn[b * SS + s] * enc[((size_t)b * SS + s) * HE + e];
    atomicAdd(&ctx[b * HE + e], sum);
}

extern "C" void kernel_launch(void* const* d_in, const int* in_sizes, int n_in,
                              void* d_out, int out_size, void* d_ws, size_t ws_size,
                              hipStream_t stream) {
    const float* enc  = (const float*)d_in[0];
    const float* dec  = (const float*)d_in[1];
    const int*   mask = (const int*)d_in[2];
    const float* W    = (const float*)d_in[3];
    const float* V    = (const float*)d_in[4];

    float* out  = (float*)d_out;
    float* ctx  = out;               // [32][1024]
    float* attn = out + BB * HE;     // [32][2048]

    // ws: wf 2M | proj 128K | psc 256K | idx 256K | cnt 4K | Zg 4K | pnum 4.5M
    const size_t WF_OFF = 0, PROJ_OFF = 2097152, PSC_OFF = PROJ_OFF + 131072,
                 IDX_OFF = PSC_OFF + 262144, CNT_OFF = IDX_OFF + 262144,
                 ZG_OFF = CNT_OFF + 4096, PN_OFF = ZG_OFF + 4096,
                 WS_NEED = PN_OFF + (size_t)576 * 2048 * 4;
    if (ws_size >= WS_NEED) {
        char* w = (char*)d_ws;
        unsigned short* wf = (unsigned short*)(w + WF_OFF);
        float* proj        = (float*)(w + PROJ_OFF);
        float* psc         = (float*)(w + PSC_OFF);
        int*   idx         = (int*)(w + IDX_OFF);
        int*   cnt         = (int*)(w + CNT_OFF);
        float* Zg          = (float*)(w + ZG_OFF);
        float* pnum        = (float*)(w + PN_OFF);

        k_prep<<<800, 256, 0, stream>>>(W, dec, mask, wf, proj, idx, cnt, Zg);
        k_scores_mfma8b<<<576, 512, 0, stream>>>(enc, wf, V, proj, idx, cnt,
                                                 psc, Zg, pnum);
        k_finish<<<160, 256, 0, stream>>>(pnum, psc, mask, Zg, cnt, ctx, attn);
    } else {
        float* proj  = ctx;
        float* score = attn;
        k_projdec2<<<256, 256, 0, stream>>>(dec, W, proj);
        k_scores_f32<<<(BB * SS) / 64, 256, 0, stream>>>(enc, W, V, proj, score);
        k_softmax_f32<<<BB, 256, 0, stream>>>(score, mask);
        hipMemsetAsync(ctx, 0, (size_t)BB * HE * sizeof(float), stream);
        k_ctx_atomic<<<dim3(BB, HE / 256, 8), 256, 0, stream>>>(enc, attn, ctx);
    }
}

// Round 15
// 173.345 us; speedup vs baseline: 1.4010x; 1.0165x over previous
//
#include <hip/hip_runtime.h>
#include <hip/hip_bf16.h>
#include <math.h>

#define BB 32
#define SS 2048
#define HE 1024
#define HD 1024
#define WROW (HE + HD)   // 2048

typedef __attribute__((ext_vector_type(8))) short bf16x8;
typedef __attribute__((ext_vector_type(4))) float f32x4;
typedef __attribute__((ext_vector_type(16))) float f32x16;
typedef __attribute__((ext_vector_type(8))) unsigned short u16x8;

__device__ __forceinline__ unsigned short f2bf(float f) {
    union { float f; unsigned u; } v; v.f = f;
    unsigned r = v.u + 0x7fffu + ((v.u >> 16) & 1u);   // RNE
    return (unsigned short)(r >> 16);
}

__device__ __forceinline__ unsigned int pk2(float x, float y) {
    union { __hip_bfloat162 h; unsigned int u; } c;
    c.h = __float22bfloat162_rn(float2{x, y});          // v_cvt_pk_bf16_f32
    return c.u;
}

#define LGKM0()  asm volatile("s_waitcnt lgkmcnt(0)" ::: "memory")
#define BAR()    asm volatile("s_barrier" ::: "memory")

// ---------------- k_prep: compact | cvt_wfrag | proj_dec fused (R10/R11) -----
__global__ __launch_bounds__(256) void k_prep(const float* __restrict__ W,
                                              const float* __restrict__ dec,
                                              const int* __restrict__ mask,
                                              unsigned short* __restrict__ wf,
                                              float* __restrict__ proj,
                                              int* __restrict__ idx,
                                              int* __restrict__ cntblk) {
    __shared__ int cb[2048];
    __shared__ int cw[4], coff[5];
    const int bx = blockIdx.x, tid = threadIdx.x;
    if (bx < 32) {
        // ---- compact: 4 waves, each scans a 512-token quarter into its slab ----
        const int b = bx, w = tid >> 6, ln = tid & 63;
        const int base = w * 512;
        int cnt = 0;
        for (int r = 0; r < 8; r++) {
            int s = base + r * 64 + ln;
            int m = mask[b * SS + s];
            unsigned long long bal = __ballot(m == 0);
            int pos = __popcll(bal & ((1ull << ln) - 1ull));
            if (m == 0) cb[base + cnt + pos] = s;
            cnt += __popcll(bal);
        }
        if (ln == 0) cw[w] = cnt;
        __syncthreads();
        if (tid == 0) {
            coff[0] = 0;
            for (int q = 0; q < 4; q++) coff[q + 1] = coff[q] + cw[q];
        }
        __syncthreads();
        const int total = coff[4];
        for (int i = tid; i < total; i += 256) {
            int q = (i >= coff[1]) + (i >= coff[2]) + (i >= coff[3]);
            idx[b * SS + i] = cb[q * 512 + (i - coff[q])];
        }
        const int padded = (total + 63) & ~63;
        for (int i = total + tid; i < padded; i += 256) idx[b * SS + i] = (int)0x80000000;
        if (tid == 0) cntblk[b] = padded >> 6;         // chunk count (<=32)
    } else if (bx < 544) {
        // ---- cvt: W_enc fp32 -> bf16 fragment-major (32x32x16 records) ----
        int i = (bx - 32) * 256 + tid;             // 0..131071 (8-elem chunks)
        int d = i >> 7;                            // 0..1023
        int c = i & 127;                           // k-chunk: k = c*8
        const float4* src = (const float4*)(W + (size_t)d * WROW + c * 8);
        float4 a = src[0], b2 = src[1];
        u16x8 o;
        o[0] = f2bf(a.x);  o[1] = f2bf(a.y);  o[2] = f2bf(a.z);  o[3] = f2bf(a.w);
        o[4] = f2bf(b2.x); o[5] = f2bf(b2.y); o[6] = f2bf(b2.z); o[7] = f2bf(b2.w);
        int ks = c >> 1;                           // k>>4
        int l  = (d & 31) + 32 * (c & 1);          // (l>>5) = k-half
        int g  = d >> 5;
        *(u16x8*)(wf + ((size_t)(g * 64 + ks) * 64 + l) * 8) = o;
    } else {
        // ---- proj_dec: W_dec read ONCE total ----
        const int dl = tid >> 6;
        const int b  = (tid >> 1) & 31;
        const int hf = tid & 1;
        const int d  = (bx - 544) * 4 + dl;
        const float* wrow = W + (size_t)d * WROW + HE + hf * 512;
        const float* dv   = dec + b * HD + hf * 512;
        float s = 0.f;
        #pragma unroll 4
        for (int e = 0; e < 512; e += 4) {
            float4 w4 = *(const float4*)(wrow + e);
            float4 x4 = *(const float4*)(dv + e);
            s += w4.x * x4.x + w4.y * x4.y + w4.z * x4.z + w4.w * x4.w;
        }
        s += __shfl_xor(s, 1, 64);
        if (hf == 0) proj[b * HD + d] = s;
    }
}

// ---------------- 8-wave 64x1024 scores + exp + partial Z + fused PV ---------
// R15: R11 body verbatim (best measured config, 171.9us e2e), with the PV
// tail vectorized: thread owns columns e={2tid,2tid+1} via float2 loads (was
// 128 scalar 4B loads + 64x 64-bit addr ops per thread). k_finish indexes
// pnum by e -> layout-agnostic. Streaming model (R14 falsified round-
// quantization): wall ~ Nblocks x T / 256, T ~ 82us; this shaves PV's share.
__global__ __launch_bounds__(512, 2) void k_scores_mfma8b(
        const float* __restrict__ enc,             // [65536][1024] fp32
        const unsigned short* __restrict__ wf,     // fragment-major bf16 W_enc
        const float* __restrict__ V,
        const float* __restrict__ proj,            // [32][1024]
        const int* __restrict__ idx,               // [32][2048] compacted tokens
        const int* __restrict__ cntblk,            // [32] chunk counts
        float* __restrict__ psc,                   // [65536] p = exp(score)
        float* __restrict__ pZ,                    // [32][32] partial Z
        float* __restrict__ pnum) {                // [32][32][1024] partial ctx num
    __shared__ unsigned short SM[8192];            // 16 KB: A dbuf [2][4096]

    const int lid = blockIdx.x;                    // no swizzle (R9: balance fix)
    int b = -1, loc = 0;
    {
        int a = 0;
        #pragma unroll
        for (int i = 0; i < 32; i++) {
            int c = cntblk[i];
            if (lid >= a && lid < a + c) { b = i; loc = lid - a; }
            a += c;
        }
    }
    if (b < 0) return;
    const int lt0 = loc << 6;

    const int tid = threadIdx.x;
    const int wv = tid >> 6, ln = tid & 63, l31 = ln & 31, hi = ln >> 5;

    // per-thread A row (K-invariant): gather via compact index
    const int rid = idx[b * SS + lt0 + (tid >> 3)];
    const size_t arow = ((size_t)b * SS + (rid & 0xffff)) * 1024;

    f32x16 acc[2][4];
    #pragma unroll
    for (int m = 0; m < 2; m++)
        #pragma unroll
        for (int n = 0; n < 4; n++)
            #pragma unroll
            for (int r = 0; r < 16; r++) acc[m][n][r] = 0.f;

    float4 areg[2];            // one K-tile of A: 64 rows x 64 k fp32, 8 fp32/thread
    bf16x8 bgE[8], bgF[8];     // B frags: [kk*4+n], E = ks 0,1  F = ks 2,3

    #define LOAD_A(k) do { \
        const float4* g_ = (const float4*)(enc + arow + (k) + (tid & 7) * 8); \
        areg[0] = g_[0]; areg[1] = g_[1]; \
    } while (0)

    #define CVTW_A(buf) do { \
        int row_ = tid >> 3; \
        union { u16x8 s; uint4 u; } pk_; \
        pk_.u.x = pk2(areg[0].x, areg[0].y); \
        pk_.u.y = pk2(areg[0].z, areg[0].w); \
        pk_.u.z = pk2(areg[1].x, areg[1].y); \
        pk_.u.w = pk2(areg[1].z, areg[1].w); \
        *(u16x8*)&SM[(buf) * 4096 + row_ * 64 + (((tid & 7) ^ (row_ & 7)) << 3)] = pk_.s; \
    } while (0)

    // B record: (g = wv*4 + n)*64 + t*4 + ksabs, lane ln
    #define LOADB(bgx, tt, ksb) do { \
        _Pragma("unroll") \
        for (int kk = 0; kk < 2; kk++) \
            _Pragma("unroll") \
            for (int n = 0; n < 4; n++) \
                bgx[kk * 4 + n] = *(const bf16x8*)(wf + ((size_t)((wv * 4 + n) * 64 + (tt) * 4 + (ksb) + kk) * 64 + ln) * 8); \
        } while (0)

    // one half-K-step (2 ks) of the wave-tile: 4 ds_reads + 16 MFMA
    #define HALF(bg, ksb, Ac) do { \
        _Pragma("unroll") \
        for (int kk = 0; kk < 2; kk++) { \
            bf16x8 af0, af1; \
            { int c_ = ((ksb) + kk) * 2 + hi; int row_ = l31; \
              af0 = *(const bf16x8*)&(Ac)[row_ * 64 + ((c_ ^ (row_ & 7)) << 3)]; } \
            { int c_ = ((ksb) + kk) * 2 + hi; int row_ = 32 + l31; \
              af1 = *(const bf16x8*)&(Ac)[row_ * 64 + ((c_ ^ (row_ & 7)) << 3)]; } \
            __builtin_amdgcn_s_setprio(1); \
            _Pragma("unroll") \
            for (int n = 0; n < 4; n++) \
                acc[0][n] = __builtin_amdgcn_mfma_f32_32x32x16_bf16(af0, bg[kk * 4 + n], acc[0][n], 0, 0, 0); \
            _Pragma("unroll") \
            for (int n = 0; n < 4; n++) \
                acc[1][n] = __builtin_amdgcn_mfma_f32_32x32x16_bf16(af1, bg[kk * 4 + n], acc[1][n], 0, 0, 0); \
            __builtin_amdgcn_s_setprio(0); \
        } } while (0)

    // ---- prologue: bg(0) both halves, A(0)->LDS, A(1) in flight ----
    LOADB(bgE, 0, 0); LOADB(bgF, 0, 2);
    LOAD_A(0);
    CVTW_A(0);                 // compiler waits A(0) loads, leaves bg in flight
    LOAD_A(64);                // A(1)
    LGKM0(); BAR();

    for (int t = 0; t < 16; ++t) {
        const int cur = t & 1, nxt = cur ^ 1;
        const unsigned short* Ac = SM + cur * 4096;

        // ks 0,1
        HALF(bgE, 0, Ac);

        // slot: bgE dead -> reload for t+1; convert A(t+1)->LDS nxt; issue A(t+2)
        if (t < 15) {
            LOADB(bgE, t + 1, 0);
            CVTW_A(nxt);                       // counted vmcnt on areg only
            if (t < 14) LOAD_A((t + 2) * 64);
        }

        // ks 2,3
        HALF(bgF, 2, Ac);

        if (t < 15) {
            LOADB(bgF, t + 1, 2);
            LGKM0(); BAR();                    // A dbuf coherence; B stays in flight
        }
    }
    #undef LOAD_A
    #undef CVTW_A
    #undef LOADB
    #undef HALF

    // ---- fused epilogue: sc[m][r] = sum_n V[d]*tanh(acc + proj) ----
    float sc[2][16];
    #pragma unroll
    for (int m = 0; m < 2; m++)
        #pragma unroll
        for (int r = 0; r < 16; r++) sc[m][r] = 0.f;
    #pragma unroll
    for (int n = 0; n < 4; n++) {
        int d = wv * 128 + n * 32 + l31;
        float pd  = proj[b * 1024 + d];
        float vv  = V[d];
        float vv2 = 2.f * vv;
        #pragma unroll
        for (int m = 0; m < 2; m++)
            #pragma unroll
            for (int r = 0; r < 16; r++) {
                float y  = acc[m][n][r] + pd;
                float e2 = __expf(2.f * y);                 // saturates at +/-inf
                float rc = __builtin_amdgcn_rcpf(e2 + 1.f);
                sc[m][r] += vv - vv2 * rc;                  // vv * tanh(y)
            }
    }

    // butterfly sum over the 32-lane column group (halves independent)
    #pragma unroll
    for (int m = 0; m < 2; m++)
        #pragma unroll
        for (int r = 0; r < 16; r++) {
            float v = sc[m][r];
            v += __shfl_xor(v, 1, 64);
            v += __shfl_xor(v, 2, 64);
            v += __shfl_xor(v, 4, 64);
            v += __shfl_xor(v, 8, 64);
            v += __shfl_xor(v, 16, 64);
            sc[m][r] = v;
        }

    __syncthreads();           // all waves done with LDS; safe to alias
    float* redf = (float*)SM;                  // [64 tok][8 wv] f32 = 2KB
    float* pf   = (float*)SM + 512;            // 64 f32: p per slot
    int*   ri   = (int*)SM + 576;              // 64 ints: local row per slot
    if (l31 == 0) {
        #pragma unroll
        for (int m = 0; m < 2; m++)
            #pragma unroll
            for (int r = 0; r < 16; r++) {
                int tok = m * 32 + (r & 3) + 8 * (r >> 2) + 4 * hi;
                redf[tok * 8 + wv] = sc[m][r];
            }
    }
    __syncthreads();
    if (tid < 64) {
        float s = 0.f;
        #pragma unroll
        for (int w = 0; w < 8; w++) s += redf[tid * 8 + w];
        int sidx = idx[b * SS + lt0 + tid];
        float p = (sidx >= 0) ? __expf(s) : 0.f;   // shift-free softmax: |s|<=51
        if (sidx >= 0) psc[b * SS + sidx] = p;
        pf[tid] = p;
        ri[tid] = sidx & 2047;                     // sentinel -> row 0 (p=0)
        float z = p;
        z += __shfl_xor(z, 1, 64);
        z += __shfl_xor(z, 2, 64);
        z += __shfl_xor(z, 4, 64);
        z += __shfl_xor(z, 8, 64);
        z += __shfl_xor(z, 16, 64);
        z += __shfl_xor(z, 32, 64);
        if (tid == 0) pZ[b * 32 + loc] = z;
    }
    __syncthreads();

    // ---- fused PV: N[e] = sum_s p_s * enc[row_s][e]; thread owns e=2tid,2tid+1
    //      float2 loads (8B/lane coalesced) halve load count + addr math ----
    float2 nv = {0.f, 0.f};
    const float* encb = enc + (size_t)b * SS * 1024;
    #pragma unroll 8
    for (int s2 = 0; s2 < 64; s2++) {
        float p = pf[s2];
        float2 v = *((const float2*)(encb + (size_t)ri[s2] * 1024) + tid);
        nv.x = fmaf(p, v.x, nv.x);
        nv.y = fmaf(p, v.y, nv.y);
    }
    *(float2*)(pnum + (size_t)(b * 32 + loc) * 1024 + 2 * tid) = nv;
}

// ---------------- finish: ctx finalize (bx<128) | attn normalize (bx>=128) ---
__global__ __launch_bounds__(256) void k_finish(const float* __restrict__ pnum,
                                                const float* __restrict__ psc,
                                                const int* __restrict__ mask,
                                                const float* __restrict__ pZ,
                                                const int* __restrict__ cntblk,
                                                float* __restrict__ ctx,
                                                float* __restrict__ attn) {
    const int bx = blockIdx.x, tid = threadIdx.x;
    if (bx < 128) {
        // ---- ctx = (sum partial N) / Z ----
        int i = bx * 256 + tid;                   // 0..32767
        int b = i >> 10, e = i & 1023;
        const int c = cntblk[b];
        float Z = 0.f;
        for (int q = 0; q < c; q++) Z += pZ[b * 32 + q];
        float s = 0.f;
        for (int q = 0; q < c; q++) s += pnum[(size_t)(b * 32 + q) * 1024 + e];
        ctx[i] = s / Z;
    } else {
        // ---- attn = mask ? 0 : p/Z ----
        const int b = bx - 128;
        const int c = cntblk[b];
        float Z = 0.f;
        for (int q = 0; q < c; q++) Z += pZ[b * 32 + q];
        float invZ = 1.f / Z;
        #pragma unroll
        for (int i = 0; i < 8; i++) {
            int s = tid + i * 256;
            int m = mask[b * SS + s];
            float p = m ? 0.f : psc[b * SS + s];
            attn[b * SS + s] = p * invZ;
        }
    }
}

// ================= fp32 fallback (round-0 proven path) =================
__global__ __launch_bounds__(256) void k_projdec2(const float* __restrict__ dec,
                                                  const float* __restrict__ W,
                                                  float* __restrict__ proj) {
    const int tid = threadIdx.x;
    const int dl = tid >> 6;
    const int b  = (tid >> 1) & 31;
    const int hf = tid & 1;
    const int d  = blockIdx.x * 4 + dl;
    const float* wrow = W + (size_t)d * WROW + HE + hf * 512;
    const float* dv   = dec + b * HD + hf * 512;
    float s = 0.f;
    #pragma unroll 4
    for (int e = 0; e < 512; e += 4) {
        float4 w4 = *(const float4*)(wrow + e);
        float4 x4 = *(const float4*)(dv + e);
        s += w4.x * x4.x + w4.y * x4.y + w4.z * x4.z + w4.w * x4.w;
    }
    s += __shfl_xor(s, 1, 64);
    if (hf == 0) proj[b * HD + d] = s;
}

__global__ __launch_bounds__(256) void k_scores_f32(const float* __restrict__ enc,
                                                    const float* __restrict__ W,
                                                    const float* __restrict__ V,
                                                    const float* __restrict__ proj,
                                                    float* __restrict__ scores) {
    __shared__ float As[64][20];
    __shared__ float Bs[64][20];
    __shared__ float red[64][17];
    const int t0 = blockIdx.x * 64;
    const int b  = t0 >> 11;
    const int tid = threadIdx.x;
    const int tx = tid & 15, ty = tid >> 4;
    const int lrow = tid >> 2, lc4 = (tid & 3) * 4;
    float sc[4] = {0.f, 0.f, 0.f, 0.f};
    for (int n0 = 0; n0 < HD; n0 += 64) {
        float C[4][4] = {};
        for (int k0 = 0; k0 < HE; k0 += 16) {
            *(float4*)&As[lrow][lc4] = *(const float4*)(enc + (size_t)(t0 + lrow) * HE + k0 + lc4);
            *(float4*)&Bs[lrow][lc4] = *(const float4*)(W + (size_t)(n0 + lrow) * WROW + k0 + lc4);
            __syncthreads();
            #pragma unroll
            for (int k4 = 0; k4 < 16; k4 += 4) {
                float4 a[4], bb[4];
                #pragma unroll
                for (int i = 0; i < 4; i++) a[i]  = *(float4*)&As[ty * 4 + i][k4];
                #pragma unroll
                for (int j = 0; j < 4; j++) bb[j] = *(float4*)&Bs[tx * 4 + j][k4];
                #pragma unroll
                for (int i = 0; i < 4; i++)
                    #pragma unroll
                    for (int j = 0; j < 4; j++)
                        C[i][j] += a[i].x * bb[j].x + a[i].y * bb[j].y +
                                   a[i].z * bb[j].z + a[i].w * bb[j].w;
            }
            __syncthreads();
        }
        #pragma unroll
        for (int j = 0; j < 4; j++) {
            int d = n0 + tx * 4 + j;
            float pd = proj[b * HD + d];
            float v  = V[d];
            #pragma unroll
            for (int i = 0; i < 4; i++) {
                float y  = C[i][j] + pd;
                float e2 = __expf(2.f * y);
                sc[i] += v * (1.f - 2.f / (e2 + 1.f));
            }
        }
    }
    #pragma unroll
    for (int i = 0; i < 4; i++) red[ty * 4 + i][tx] = sc[i];
    __syncthreads();
    if (tid < 64) {
        float s = 0.f;
        #pragma unroll
        for (int x = 0; x < 16; x++) s += red[tid][x];
        scores[t0 + tid] = s;
    }
}

__global__ __launch_bounds__(256) void k_softmax_f32(float* __restrict__ sc_attn,
                                                     const int* __restrict__ mask) {
    __shared__ float sred[256];
    const int b = blockIdx.x, tid = threadIdx.x;
    float vals[8]; int msk[8];
    float lmax = -1e30f;
    #pragma unroll
    for (int i = 0; i < 8; i++) {
        int s = tid + i * 256;
        vals[i] = sc_attn[b * SS + s];
        msk[i]  = mask[b * SS + s];
        if (!msk[i]) lmax = fmaxf(lmax, vals[i]);
    }
    sred[tid] = lmax; __syncthreads();
    for (int off = 128; off > 0; off >>= 1) {
        if (tid < off) sred[tid] = fmaxf(sred[tid], sred[tid + off]);
        __syncthreads();
    }
    float m = sred[0];
    __syncthreads();
    float ex[8]; float lsum = 0.f;
    #pragma unroll
    for (int i = 0; i < 8; i++) { ex[i] = msk[i] ? 0.f : __expf(vals[i] - m); lsum += ex[i]; }
    sred[tid] = lsum; __syncthreads();
    for (int off = 128; off > 0; off >>= 1) {
        if (tid < off) sred[tid] += sred[tid + off];
        __syncthreads();
    }
    float inv = 1.f / sred[0];
    #pragma unroll
    for (int i = 0; i < 8; i++) sc_attn[b * SS + tid + i * 256] = ex[i] * inv;
}

__global__ __launch_bounds__(256) void k_ctx_atomic(const float* __restrict__ enc,
                                                    const float* __restrict__ attn,
                                                    float* __restrict__ ctx) {
    const int b = blockIdx.x;
    const int e = blockIdx.y * 256 + threadIdx.x;
    const int s0 = blockIdx.z * 256;
    float sum = 0.f;
    for (int s = s0; s < s0 + 256; s++)
        sum += attn[b * SS + s] * enc[((size_t)b * SS + s) * HE + e];
    atomicAdd(&ctx[b * HE + e], sum);
}

extern "C" void kernel_launch(void* const* d_in, const int* in_sizes, int n_in,
                              void* d_out, int out_size, void* d_ws, size_t ws_size,
                              hipStream_t stream) {
    const float* enc  = (const float*)d_in[0];
    const float* dec  = (const float*)d_in[1];
    const int*   mask = (const int*)d_in[2];
    const float* W    = (const float*)d_in[3];
    const float* V    = (const float*)d_in[4];

    float* out  = (float*)d_out;
    float* ctx  = out;               // [32][1024]
    float* attn = out + BB * HE;     // [32][2048]

    // ws layout (bytes): wf 2M | proj 128K | psc 256K | idx 256K | cnt 4K | pZ 4K | pnum 4M
    const size_t WF_OFF = 0, PROJ_OFF = 2097152, PSC_OFF = PROJ_OFF + 131072,
                 IDX_OFF = PSC_OFF + 262144, CNT_OFF = IDX_OFF + 262144,
                 PZ_OFF = CNT_OFF + 4096, PN_OFF = PZ_OFF + 4096,
                 WS_NEED = PN_OFF + 4194304;
    if (ws_size >= WS_NEED) {
        char* w = (char*)d_ws;
        unsigned short* wf = (unsigned short*)(w + WF_OFF);
        float* proj        = (float*)(w + PROJ_OFF);
        float* psc         = (float*)(w + PSC_OFF);
        int*   idx         = (int*)(w + IDX_OFF);
        int*   cntblk      = (int*)(w + CNT_OFF);
        float* pZ          = (float*)(w + PZ_OFF);
        float* pnum        = (float*)(w + PN_OFF);

        k_prep<<<800, 256, 0, stream>>>(W, dec, mask, wf, proj, idx, cntblk);
        k_scores_mfma8b<<<1024, 512, 0, stream>>>(enc, wf, V, proj, idx, cntblk,
                                                  psc, pZ, pnum);
        k_finish<<<160, 256, 0, stream>>>(pnum, psc, mask, pZ, cntblk, ctx, attn);
    } else {
        float* proj  = ctx;
        float* score = attn;
        k_projdec2<<<256, 256, 0, stream>>>(dec, W, proj);
        k_scores_f32<<<(BB * SS) / 64, 256, 0, stream>>>(enc, W, V, proj, score);
        k_softmax_f32<<<BB, 256, 0, stream>>>(score, mask);
        hipMemsetAsync(ctx, 0, (size_t)BB * HE * sizeof(float), stream);
        k_ctx_atomic<<<dim3(BB, HE / 256, 8), 256, 0, stream>>>(enc, attn, ctx);
    }
}